// Round 1
// baseline (895.695 us; speedup 1.0000x reference)
//
#include <hip/hip_runtime.h>
#include <math.h>

#define N_NODES 50000
#define N_EDGES 800000
#define ETOT    (N_EDGES + N_NODES)
#define IN_CH   128
#define HID     64
#define HEADS   4
#define OUT_CH  40
#define NEG     0.2f

// ---------------------------------------------------------------------------
// CSR build: histogram of dst, exclusive scan, scatter src indices
// ---------------------------------------------------------------------------
__global__ void k_hist(const int* __restrict__ ei, int* __restrict__ deg) {
    int i = blockIdx.x * blockDim.x + threadIdx.x;
    if (i >= ETOT) return;
    int d = (i < N_EDGES) ? ei[N_EDGES + i] : (i - N_EDGES);
    atomicAdd(&deg[d], 1);
}

__global__ void k_scan1(const int* __restrict__ deg, int* __restrict__ start,
                        int* __restrict__ bsum) {
    __shared__ int sh[256];
    int tid = threadIdx.x;
    int i = blockIdx.x * 256 + tid;
    int v = (i < N_NODES) ? deg[i] : 0;
    int x = v;
    sh[tid] = x;
    __syncthreads();
    #pragma unroll
    for (int off = 1; off < 256; off <<= 1) {
        int t = (tid >= off) ? sh[tid - off] : 0;
        __syncthreads();
        x += t;
        sh[tid] = x;
        __syncthreads();
    }
    if (i < N_NODES) start[i] = x - v;        // exclusive within block
    if (tid == 255) bsum[blockIdx.x] = x;     // block total
}

__global__ void k_scan2(int* __restrict__ bsum, int nb) {
    __shared__ int sh[256];
    int tid = threadIdx.x;
    int v = (tid < nb) ? bsum[tid] : 0;
    int x = v;
    sh[tid] = x;
    __syncthreads();
    #pragma unroll
    for (int off = 1; off < 256; off <<= 1) {
        int t = (tid >= off) ? sh[tid - off] : 0;
        __syncthreads();
        x += t;
        sh[tid] = x;
        __syncthreads();
    }
    if (tid < nb) bsum[tid] = x - v;          // exclusive
}

__global__ void k_scan3(int* __restrict__ start, const int* __restrict__ bsum) {
    int i = blockIdx.x * 256 + threadIdx.x;
    if (i < N_NODES) start[i] += bsum[blockIdx.x];
}

__global__ void k_scatter(const int* __restrict__ ei, const int* __restrict__ start,
                          int* __restrict__ fill, int* __restrict__ eSrc) {
    int i = blockIdx.x * blockDim.x + threadIdx.x;
    if (i >= ETOT) return;
    int s, d;
    if (i < N_EDGES) { s = ei[i]; d = ei[N_EDGES + i]; }
    else             { s = i - N_EDGES; d = s; }
    int pos = start[d] + atomicAdd(&fill[d], 1);
    eSrc[pos] = s;
}

// ---------------------------------------------------------------------------
// Tiled fp32 GEMM: C[M,Ncol] = A[M,K] @ B[K,Ncol]   (row-major, no bias)
// 64x64 tile, 256 threads, 4x4 per thread
// ---------------------------------------------------------------------------
#define BM 64
#define BN 64
#define BK 16
__global__ __launch_bounds__(256) void k_gemm(const float* __restrict__ A,
                                              const float* __restrict__ B,
                                              float* __restrict__ C,
                                              int M, int K, int Ncol) {
    __shared__ float As[BK][BM + 1];
    __shared__ float Bs[BK][BN + 1];
    int tid = threadIdx.x;
    int tx = tid & 15, ty = tid >> 4;
    int row0 = blockIdx.x * BM;
    int col0 = blockIdx.y * BN;
    float acc[4][4] = {};
    for (int k0 = 0; k0 < K; k0 += BK) {
        for (int l = tid; l < BM * BK; l += 256) {
            int r = l >> 4, c = l & 15;
            int gr = row0 + r;
            As[c][r] = (gr < M) ? A[(long)gr * K + k0 + c] : 0.f;
        }
        for (int l = tid; l < BK * BN; l += 256) {
            int r = l >> 6, c = l & 63;
            int gc = col0 + c;
            Bs[r][c] = (gc < Ncol) ? B[(long)(k0 + r) * Ncol + gc] : 0.f;
        }
        __syncthreads();
        #pragma unroll
        for (int kk = 0; kk < BK; ++kk) {
            float a[4], b[4];
            #pragma unroll
            for (int i = 0; i < 4; ++i) a[i] = As[kk][ty * 4 + i];
            #pragma unroll
            for (int j = 0; j < 4; ++j) b[j] = Bs[kk][tx * 4 + j];
            #pragma unroll
            for (int i = 0; i < 4; ++i)
                #pragma unroll
                for (int j = 0; j < 4; ++j)
                    acc[i][j] += a[i] * b[j];
        }
        __syncthreads();
    }
    #pragma unroll
    for (int i = 0; i < 4; ++i) {
        int gr = row0 + ty * 4 + i;
        if (gr >= M) continue;
        #pragma unroll
        for (int j = 0; j < 4; ++j) {
            int gc = col0 + tx * 4 + j;
            if (gc < Ncol) C[(long)gr * Ncol + gc] = acc[i][j];
        }
    }
}

// ---------------------------------------------------------------------------
// Attention logits: als[n,h] = dot(h[n,h,:], a_src[h,:]) ; same for ald
// 4-head layers: one wave per node, lane owns 4 consecutive channels
// ---------------------------------------------------------------------------
__global__ __launch_bounds__(256) void k_logits4(const float* __restrict__ h,
                                                 const float* __restrict__ a_s,
                                                 const float* __restrict__ a_d,
                                                 float* __restrict__ als,
                                                 float* __restrict__ ald) {
    int wave = (blockIdx.x * blockDim.x + threadIdx.x) >> 6;
    int lane = threadIdx.x & 63;
    if (wave >= N_NODES) return;
    float4 hv = *(const float4*)(h + (long)wave * 256 + lane * 4);
    int head = lane >> 4;
    int cbase = (lane * 4) & 63;
    float4 sv = *(const float4*)(a_s + head * 64 + cbase);
    float4 dv = *(const float4*)(a_d + head * 64 + cbase);
    float ps = hv.x * sv.x + hv.y * sv.y + hv.z * sv.z + hv.w * sv.w;
    float pd = hv.x * dv.x + hv.y * dv.y + hv.z * dv.z + hv.w * dv.w;
    #pragma unroll
    for (int off = 1; off < 16; off <<= 1) {
        ps += __shfl_xor(ps, off);
        pd += __shfl_xor(pd, off);
    }
    if ((lane & 15) == 0) {
        als[wave * 4 + head] = ps;
        ald[wave * 4 + head] = pd;
    }
}

// single-head layer (C=40)
__global__ __launch_bounds__(256) void k_logits1(const float* __restrict__ h,
                                                 const float* __restrict__ a_s,
                                                 const float* __restrict__ a_d,
                                                 float* __restrict__ als,
                                                 float* __restrict__ ald) {
    int wave = (blockIdx.x * blockDim.x + threadIdx.x) >> 6;
    int lane = threadIdx.x & 63;
    if (wave >= N_NODES) return;
    float hv = (lane < OUT_CH) ? h[(long)wave * OUT_CH + lane] : 0.f;
    float ps = (lane < OUT_CH) ? hv * a_s[lane] : 0.f;
    float pd = (lane < OUT_CH) ? hv * a_d[lane] : 0.f;
    #pragma unroll
    for (int off = 1; off < 64; off <<= 1) {
        ps += __shfl_xor(ps, off);
        pd += __shfl_xor(pd, off);
    }
    if (lane == 0) {
        als[wave] = ps;
        ald[wave] = pd;
    }
}

// ---------------------------------------------------------------------------
// Aggregation with online softmax. 4-head layers: one wave per node,
// lane owns channels [lane*4, lane*4+4) of the 256 (head = lane>>4).
// out = relu(agg + bias)
// ---------------------------------------------------------------------------
__global__ __launch_bounds__(256) void k_agg4(const float* __restrict__ h,
                                              const int* __restrict__ start,
                                              const int* __restrict__ deg,
                                              const int* __restrict__ eSrc,
                                              const float* __restrict__ als,
                                              const float* __restrict__ ald,
                                              const float* __restrict__ bias,
                                              float* __restrict__ out) {
    int node = (blockIdx.x * blockDim.x + threadIdx.x) >> 6;
    int lane = threadIdx.x & 63;
    if (node >= N_NODES) return;
    int st = start[node];
    int dg = deg[node];
    int head = lane >> 4;
    float aldd = ald[node * 4 + head];
    float m = -INFINITY, den = 0.f;
    float4 acc = {0.f, 0.f, 0.f, 0.f};
    for (int j = 0; j < dg; ++j) {
        int s = eSrc[st + j];
        float a = als[s * 4 + head] + aldd;
        a = (a > 0.f) ? a : NEG * a;
        float nm = fmaxf(m, a);
        float sc = __expf(m - nm);   // first iter: exp(-inf) = 0
        float w = __expf(a - nm);
        float4 hv = *(const float4*)(h + (long)s * 256 + lane * 4);
        den = den * sc + w;
        acc.x = acc.x * sc + w * hv.x;
        acc.y = acc.y * sc + w * hv.y;
        acc.z = acc.z * sc + w * hv.z;
        acc.w = acc.w * sc + w * hv.w;
        m = nm;
    }
    float inv = 1.f / den;
    int c = lane * 4;
    float4 bv = *(const float4*)(bias + c);
    float4 o;
    o.x = fmaxf(acc.x * inv + bv.x, 0.f);
    o.y = fmaxf(acc.y * inv + bv.y, 0.f);
    o.z = fmaxf(acc.z * inv + bv.z, 0.f);
    o.w = fmaxf(acc.w * inv + bv.w, 0.f);
    *(float4*)(out + (long)node * 256 + c) = o;
}

// final layer: 1 head, C=40, fused bias + log_softmax
__global__ __launch_bounds__(256) void k_agg1(const float* __restrict__ h,
                                              const int* __restrict__ start,
                                              const int* __restrict__ deg,
                                              const int* __restrict__ eSrc,
                                              const float* __restrict__ als,
                                              const float* __restrict__ ald,
                                              const float* __restrict__ bias,
                                              float* __restrict__ out) {
    int node = (blockIdx.x * blockDim.x + threadIdx.x) >> 6;
    int lane = threadIdx.x & 63;
    if (node >= N_NODES) return;
    int st = start[node];
    int dg = deg[node];
    float aldd = ald[node];
    float m = -INFINITY, den = 0.f, acc = 0.f;
    for (int j = 0; j < dg; ++j) {
        int s = eSrc[st + j];
        float a = als[s] + aldd;
        a = (a > 0.f) ? a : NEG * a;
        float nm = fmaxf(m, a);
        float sc = __expf(m - nm);
        float w = __expf(a - nm);
        float hv = (lane < OUT_CH) ? h[(long)s * OUT_CH + lane] : 0.f;
        den = den * sc + w;
        acc = acc * sc + w * hv;
        m = nm;
    }
    float v = acc / den + ((lane < OUT_CH) ? bias[lane] : 0.f);
    // log_softmax over lanes 0..39
    float vm = (lane < OUT_CH) ? v : -INFINITY;
    float mx = vm;
    #pragma unroll
    for (int off = 1; off < 64; off <<= 1) mx = fmaxf(mx, __shfl_xor(mx, off));
    float ex = (lane < OUT_CH) ? __expf(v - mx) : 0.f;
    float sum = ex;
    #pragma unroll
    for (int off = 1; off < 64; off <<= 1) sum += __shfl_xor(sum, off);
    float res = v - mx - logf(sum);
    if (lane < OUT_CH) out[(long)node * OUT_CH + lane] = res;
}

// ---------------------------------------------------------------------------
extern "C" void kernel_launch(void* const* d_in, const int* in_sizes, int n_in,
                              void* d_out, int out_size, void* d_ws, size_t ws_size,
                              hipStream_t stream) {
    (void)in_sizes; (void)n_in; (void)out_size; (void)ws_size;
    const float* x   = (const float*)d_in[0];
    const int*   ei  = (const int*)d_in[1];
    const float* W1  = (const float*)d_in[2];
    const float* as1 = (const float*)d_in[3];
    const float* ad1 = (const float*)d_in[4];
    const float* b1  = (const float*)d_in[5];
    const float* W2  = (const float*)d_in[6];
    const float* as2 = (const float*)d_in[7];
    const float* ad2 = (const float*)d_in[8];
    const float* b2  = (const float*)d_in[9];
    const float* W3  = (const float*)d_in[10];
    const float* as3 = (const float*)d_in[11];
    const float* ad3 = (const float*)d_in[12];
    const float* b3  = (const float*)d_in[13];
    float* out = (float*)d_out;

    char* p = (char*)d_ws;
    auto alloc = [&](size_t b) { char* r = p; p += (b + 255) & ~(size_t)255; return r; };
    int*   deg   = (int*)alloc((size_t)N_NODES * 4);
    int*   start = (int*)alloc((size_t)N_NODES * 4);
    int*   fill  = (int*)alloc((size_t)N_NODES * 4);
    int*   bsum  = (int*)alloc(256 * 4);
    int*   eSrc  = (int*)alloc((size_t)ETOT * 4);
    float* hA    = (float*)alloc((size_t)N_NODES * 256 * 4);
    float* hB    = (float*)alloc((size_t)N_NODES * 256 * 4);
    float* h3    = (float*)alloc((size_t)N_NODES * OUT_CH * 4);
    float* als   = (float*)alloc((size_t)N_NODES * 4 * 4);
    float* ald   = (float*)alloc((size_t)N_NODES * 4 * 4);

    const int NB = (N_NODES + 255) / 256;            // 196 scan blocks
    const int EB = (ETOT + 255) / 256;               // edge blocks
    const int WB = (N_NODES + 3) / 4;                // wave-per-node blocks (256 thr)

    // ---- CSR build ----
    hipMemsetAsync(deg,  0, (size_t)N_NODES * 4, stream);
    hipMemsetAsync(fill, 0, (size_t)N_NODES * 4, stream);
    k_hist<<<EB, 256, 0, stream>>>(ei, deg);
    k_scan1<<<NB, 256, 0, stream>>>(deg, start, bsum);
    k_scan2<<<1, 256, 0, stream>>>(bsum, NB);
    k_scan3<<<NB, 256, 0, stream>>>(start, bsum);
    k_scatter<<<EB, 256, 0, stream>>>(ei, start, fill, eSrc);

    // ---- layer 1 ----
    {
        dim3 g((N_NODES + BM - 1) / BM, 256 / BN);
        k_gemm<<<g, 256, 0, stream>>>(x, W1, hA, N_NODES, IN_CH, 256);
    }
    k_logits4<<<WB, 256, 0, stream>>>(hA, as1, ad1, als, ald);
    k_agg4<<<WB, 256, 0, stream>>>(hA, start, deg, eSrc, als, ald, b1, hB);

    // ---- layer 2 ----
    {
        dim3 g((N_NODES + BM - 1) / BM, 256 / BN);
        k_gemm<<<g, 256, 0, stream>>>(hB, W2, hA, N_NODES, 256, 256);
    }
    k_logits4<<<WB, 256, 0, stream>>>(hA, as2, ad2, als, ald);
    k_agg4<<<WB, 256, 0, stream>>>(hA, start, deg, eSrc, als, ald, b2, hB);

    // ---- layer 3 ----
    {
        dim3 g((N_NODES + BM - 1) / BM, 1);
        k_gemm<<<g, 256, 0, stream>>>(hB, W3, h3, N_NODES, 256, OUT_CH);
    }
    k_logits1<<<WB, 256, 0, stream>>>(h3, as3, ad3, als, ald);
    k_agg1<<<WB, 256, 0, stream>>>(h3, start, deg, eSrc, als, ald, b3, out);
}

// Round 2
// 636.406 us; speedup vs baseline: 1.4074x; 1.4074x over previous
//
#include <hip/hip_runtime.h>
#include <math.h>

#define N_NODES 50000
#define N_EDGES 800000
#define ETOT    (N_EDGES + N_NODES)
#define IN_CH   128
#define OUT_CH  40
#define NEG     0.2f

typedef __attribute__((ext_vector_type(8))) short bf16x8;
typedef __attribute__((ext_vector_type(4))) float f32x4;

__device__ inline unsigned short f2bf(float f) {
    unsigned int u = __float_as_uint(f);
    return (unsigned short)((u + 0x7FFFu + ((u >> 16) & 1u)) >> 16);
}

// ---------------------------------------------------------------------------
// CSR build: histogram of dst, exclusive scan, scatter src indices
// ---------------------------------------------------------------------------
__global__ void k_hist(const int* __restrict__ ei, int* __restrict__ deg) {
    int i = blockIdx.x * blockDim.x + threadIdx.x;
    if (i >= ETOT) return;
    int d = (i < N_EDGES) ? ei[N_EDGES + i] : (i - N_EDGES);
    atomicAdd(&deg[d], 1);
}

__global__ void k_scan1(const int* __restrict__ deg, int* __restrict__ start,
                        int* __restrict__ bsum) {
    __shared__ int sh[256];
    int tid = threadIdx.x;
    int i = blockIdx.x * 256 + tid;
    int v = (i < N_NODES) ? deg[i] : 0;
    int x = v;
    sh[tid] = x;
    __syncthreads();
    #pragma unroll
    for (int off = 1; off < 256; off <<= 1) {
        int t = (tid >= off) ? sh[tid - off] : 0;
        __syncthreads();
        x += t;
        sh[tid] = x;
        __syncthreads();
    }
    if (i < N_NODES) start[i] = x - v;
    if (tid == 255) bsum[blockIdx.x] = x;
}

__global__ void k_scan2(int* __restrict__ bsum, int nb) {
    __shared__ int sh[256];
    int tid = threadIdx.x;
    int v = (tid < nb) ? bsum[tid] : 0;
    int x = v;
    sh[tid] = x;
    __syncthreads();
    #pragma unroll
    for (int off = 1; off < 256; off <<= 1) {
        int t = (tid >= off) ? sh[tid - off] : 0;
        __syncthreads();
        x += t;
        sh[tid] = x;
        __syncthreads();
    }
    if (tid < nb) bsum[tid] = x - v;
}

__global__ void k_scan3(int* __restrict__ start, const int* __restrict__ bsum) {
    int i = blockIdx.x * 256 + threadIdx.x;
    if (i < N_NODES) start[i] += bsum[blockIdx.x];
}

__global__ void k_scatter(const int* __restrict__ ei, const int* __restrict__ start,
                          int* __restrict__ fill, int* __restrict__ eSrc) {
    int i = blockIdx.x * blockDim.x + threadIdx.x;
    if (i >= ETOT) return;
    int s, d;
    if (i < N_EDGES) { s = ei[i]; d = ei[N_EDGES + i]; }
    else             { s = i - N_EDGES; d = s; }
    int pos = start[d] + atomicAdd(&fill[d], 1);
    eSrc[pos] = s;
}

// ---------------------------------------------------------------------------
// Cast helpers: fp32 -> bf16 (activations), W[K][N] fp32 -> Wt[Npad][K] bf16
// ---------------------------------------------------------------------------
__global__ void k_cast4(const float* __restrict__ in, unsigned short* __restrict__ out,
                        int n4) {
    int i = blockIdx.x * blockDim.x + threadIdx.x;
    if (i >= n4) return;
    float4 v = ((const float4*)in)[i];
    ushort4 o;
    o.x = f2bf(v.x); o.y = f2bf(v.y); o.z = f2bf(v.z); o.w = f2bf(v.w);
    ((ushort4*)out)[i] = o;
}

__global__ void k_wt(const float* __restrict__ W, unsigned short* __restrict__ Wt,
                     int K, int Ncol, int Npad) {
    int i = blockIdx.x * blockDim.x + threadIdx.x;
    if (i >= Npad * K) return;
    int n = i / K, k = i - n * K;
    Wt[n * K + k] = (n < Ncol) ? f2bf(W[(long)k * Ncol + n]) : (unsigned short)0;
}

// ---------------------------------------------------------------------------
// bf16 MFMA GEMM: C[M,Ncol] = A[M,K] @ B[K,Ncol], B given pre-transposed
// bf16 Bt[Npad][K]. 128 x BN block tile, 4 waves, 16x16x32 MFMA.
// BN=128: waves 2x2 (wave tile 64x64, FM=4,FN=4)
// BN=64 : waves 4x1 (wave tile 32x64, FM=2,FN=4)
// ---------------------------------------------------------------------------
#define PITCH 40   // bf16 elements per LDS row (32 data + 8 pad) = 80 B
template<int BN, int FM, int FN>
__global__ __launch_bounds__(256) void k_mfma(const unsigned short* __restrict__ A,
                                              const unsigned short* __restrict__ Bt,
                                              float* __restrict__ C,
                                              int M, int K, int Ncol) {
    __shared__ unsigned short As[128 * PITCH];
    __shared__ unsigned short Bs[BN * PITCH];
    const int WCOLS = BN / (FN * 16);
    int tid = threadIdx.x;
    int wave = tid >> 6, lane = tid & 63;
    int quad = lane >> 4, l16 = lane & 15;
    int wr = wave / WCOLS, wc = wave % WCOLS;
    long row0 = (long)blockIdx.x * 128;
    int col0 = blockIdx.y * BN;

    f32x4 acc[FM][FN] = {};

    for (int k0 = 0; k0 < K; k0 += 32) {
        // stage A tile: 128 rows x 32 k, 8-bf16 (16B) chunks
        for (int c = tid; c < 512; c += 256) {
            int r = c >> 2, kp = (c & 3) << 3;
            long gr = row0 + r;
            uint4 v = {0u, 0u, 0u, 0u};
            if (gr < M) v = *(const uint4*)(A + gr * K + k0 + kp);
            *(uint4*)(As + r * PITCH + kp) = v;
        }
        // stage B tile: BN rows x 32 k (Bt is padded to Npad >= col0+BN)
        for (int c = tid; c < BN * 4; c += 256) {
            int r = c >> 2, kp = (c & 3) << 3;
            uint4 v = *(const uint4*)(Bt + (long)(col0 + r) * K + k0 + kp);
            *(uint4*)(Bs + r * PITCH + kp) = v;
        }
        __syncthreads();
        bf16x8 af[FM], bfr[FN];
        #pragma unroll
        for (int i = 0; i < FM; ++i)
            af[i] = *(const bf16x8*)(As + (wr * FM * 16 + i * 16 + l16) * PITCH + quad * 8);
        #pragma unroll
        for (int j = 0; j < FN; ++j)
            bfr[j] = *(const bf16x8*)(Bs + (wc * FN * 16 + j * 16 + l16) * PITCH + quad * 8);
        #pragma unroll
        for (int i = 0; i < FM; ++i)
            #pragma unroll
            for (int j = 0; j < FN; ++j)
                acc[i][j] = __builtin_amdgcn_mfma_f32_16x16x32_bf16(af[i], bfr[j], acc[i][j], 0, 0, 0);
        __syncthreads();
    }

    #pragma unroll
    for (int i = 0; i < FM; ++i) {
        long rowb = row0 + wr * FM * 16 + i * 16 + quad * 4;
        #pragma unroll
        for (int j = 0; j < FN; ++j) {
            int col = col0 + wc * FN * 16 + j * 16 + l16;
            if (col < Ncol) {
                #pragma unroll
                for (int v = 0; v < 4; ++v) {
                    long r = rowb + v;
                    if (r < M) C[r * Ncol + col] = acc[i][j][v];
                }
            }
        }
    }
}

// ---------------------------------------------------------------------------
// Attention logits (4-head layers): one wave per node
// ---------------------------------------------------------------------------
__global__ __launch_bounds__(256) void k_logits4(const float* __restrict__ h,
                                                 const float* __restrict__ a_s,
                                                 const float* __restrict__ a_d,
                                                 float* __restrict__ als,
                                                 float* __restrict__ ald) {
    int wave = (blockIdx.x * blockDim.x + threadIdx.x) >> 6;
    int lane = threadIdx.x & 63;
    if (wave >= N_NODES) return;
    float4 hv = *(const float4*)(h + (long)wave * 256 + lane * 4);
    int head = lane >> 4;
    int cbase = (lane * 4) & 63;
    float4 sv = *(const float4*)(a_s + head * 64 + cbase);
    float4 dv = *(const float4*)(a_d + head * 64 + cbase);
    float ps = hv.x * sv.x + hv.y * sv.y + hv.z * sv.z + hv.w * sv.w;
    float pd = hv.x * dv.x + hv.y * dv.y + hv.z * dv.z + hv.w * dv.w;
    #pragma unroll
    for (int off = 1; off < 16; off <<= 1) {
        ps += __shfl_xor(ps, off);
        pd += __shfl_xor(pd, off);
    }
    if ((lane & 15) == 0) {
        als[wave * 4 + head] = ps;
        ald[wave * 4 + head] = pd;
    }
}

__global__ __launch_bounds__(256) void k_logits1(const float* __restrict__ h,
                                                 const float* __restrict__ a_s,
                                                 const float* __restrict__ a_d,
                                                 float* __restrict__ als,
                                                 float* __restrict__ ald) {
    int wave = (blockIdx.x * blockDim.x + threadIdx.x) >> 6;
    int lane = threadIdx.x & 63;
    if (wave >= N_NODES) return;
    float hv = (lane < OUT_CH) ? h[(long)wave * OUT_CH + lane] : 0.f;
    float ps = (lane < OUT_CH) ? hv * a_s[lane] : 0.f;
    float pd = (lane < OUT_CH) ? hv * a_d[lane] : 0.f;
    #pragma unroll
    for (int off = 1; off < 64; off <<= 1) {
        ps += __shfl_xor(ps, off);
        pd += __shfl_xor(pd, off);
    }
    if (lane == 0) {
        als[wave] = ps;
        ald[wave] = pd;
    }
}

// ---------------------------------------------------------------------------
// Aggregation + online softmax (4-head layers). Writes bf16 (feeds next GEMM).
// out = relu(agg + bias)
// ---------------------------------------------------------------------------
__global__ __launch_bounds__(256) void k_agg4(const float* __restrict__ h,
                                              const int* __restrict__ start,
                                              const int* __restrict__ deg,
                                              const int* __restrict__ eSrc,
                                              const float* __restrict__ als,
                                              const float* __restrict__ ald,
                                              const float* __restrict__ bias,
                                              unsigned short* __restrict__ out) {
    int node = (blockIdx.x * blockDim.x + threadIdx.x) >> 6;
    int lane = threadIdx.x & 63;
    if (node >= N_NODES) return;
    int st = start[node];
    int dg = deg[node];
    int head = lane >> 4;
    float aldd = ald[node * 4 + head];
    float m = -INFINITY, den = 0.f;
    float4 acc = {0.f, 0.f, 0.f, 0.f};
    for (int j = 0; j < dg; ++j) {
        int s = eSrc[st + j];
        float a = als[s * 4 + head] + aldd;
        a = (a > 0.f) ? a : NEG * a;
        float nm = fmaxf(m, a);
        float sc = __expf(m - nm);
        float w = __expf(a - nm);
        float4 hv = *(const float4*)(h + (long)s * 256 + lane * 4);
        den = den * sc + w;
        acc.x = acc.x * sc + w * hv.x;
        acc.y = acc.y * sc + w * hv.y;
        acc.z = acc.z * sc + w * hv.z;
        acc.w = acc.w * sc + w * hv.w;
        m = nm;
    }
    float inv = 1.f / den;
    int c = lane * 4;
    float4 bv = *(const float4*)(bias + c);
    ushort4 o;
    o.x = f2bf(fmaxf(acc.x * inv + bv.x, 0.f));
    o.y = f2bf(fmaxf(acc.y * inv + bv.y, 0.f));
    o.z = f2bf(fmaxf(acc.z * inv + bv.z, 0.f));
    o.w = f2bf(fmaxf(acc.w * inv + bv.w, 0.f));
    *(ushort4*)(out + (long)node * 256 + c) = o;
}

// final layer: 1 head, C=40, fused bias + log_softmax (fp32 out)
__global__ __launch_bounds__(256) void k_agg1(const float* __restrict__ h,
                                              const int* __restrict__ start,
                                              const int* __restrict__ deg,
                                              const int* __restrict__ eSrc,
                                              const float* __restrict__ als,
                                              const float* __restrict__ ald,
                                              const float* __restrict__ bias,
                                              float* __restrict__ out) {
    int node = (blockIdx.x * blockDim.x + threadIdx.x) >> 6;
    int lane = threadIdx.x & 63;
    if (node >= N_NODES) return;
    int st = start[node];
    int dg = deg[node];
    float aldd = ald[node];
    float m = -INFINITY, den = 0.f, acc = 0.f;
    for (int j = 0; j < dg; ++j) {
        int s = eSrc[st + j];
        float a = als[s] + aldd;
        a = (a > 0.f) ? a : NEG * a;
        float nm = fmaxf(m, a);
        float sc = __expf(m - nm);
        float w = __expf(a - nm);
        float hv = (lane < OUT_CH) ? h[(long)s * OUT_CH + lane] : 0.f;
        den = den * sc + w;
        acc = acc * sc + w * hv;
        m = nm;
    }
    float v = acc / den + ((lane < OUT_CH) ? bias[lane] : 0.f);
    float vm = (lane < OUT_CH) ? v : -INFINITY;
    float mx = vm;
    #pragma unroll
    for (int off = 1; off < 64; off <<= 1) mx = fmaxf(mx, __shfl_xor(mx, off));
    float ex = (lane < OUT_CH) ? __expf(v - mx) : 0.f;
    float sum = ex;
    #pragma unroll
    for (int off = 1; off < 64; off <<= 1) sum += __shfl_xor(sum, off);
    float res = v - mx - logf(sum);
    if (lane < OUT_CH) out[(long)node * OUT_CH + lane] = res;
}

// ---------------------------------------------------------------------------
extern "C" void kernel_launch(void* const* d_in, const int* in_sizes, int n_in,
                              void* d_out, int out_size, void* d_ws, size_t ws_size,
                              hipStream_t stream) {
    (void)in_sizes; (void)n_in; (void)out_size; (void)ws_size;
    const float* x   = (const float*)d_in[0];
    const int*   ei  = (const int*)d_in[1];
    const float* W1  = (const float*)d_in[2];
    const float* as1 = (const float*)d_in[3];
    const float* ad1 = (const float*)d_in[4];
    const float* b1  = (const float*)d_in[5];
    const float* W2  = (const float*)d_in[6];
    const float* as2 = (const float*)d_in[7];
    const float* ad2 = (const float*)d_in[8];
    const float* b2  = (const float*)d_in[9];
    const float* W3  = (const float*)d_in[10];
    const float* as3 = (const float*)d_in[11];
    const float* ad3 = (const float*)d_in[12];
    const float* b3  = (const float*)d_in[13];
    float* out = (float*)d_out;

    char* p = (char*)d_ws;
    auto alloc = [&](size_t b) { char* r = p; p += (b + 255) & ~(size_t)255; return r; };
    int*   deg   = (int*)alloc((size_t)N_NODES * 4);
    int*   start = (int*)alloc((size_t)N_NODES * 4);
    int*   fill  = (int*)alloc((size_t)N_NODES * 4);
    int*   bsum  = (int*)alloc(256 * 4);
    int*   eSrc  = (int*)alloc((size_t)ETOT * 4);
    float* hA    = (float*)alloc((size_t)N_NODES * 256 * 4);   // fp32 GEMM out (attention src)
    float* h3    = (float*)alloc((size_t)N_NODES * OUT_CH * 4);
    float* als   = (float*)alloc((size_t)N_NODES * 4 * 4);
    float* ald   = (float*)alloc((size_t)N_NODES * 4 * 4);
    unsigned short* xbf  = (unsigned short*)alloc((size_t)N_NODES * IN_CH * 2);
    unsigned short* hBbf = (unsigned short*)alloc((size_t)N_NODES * 256 * 2);  // agg out (GEMM in)
    unsigned short* Wt1  = (unsigned short*)alloc((size_t)256 * IN_CH * 2);
    unsigned short* Wt2  = (unsigned short*)alloc((size_t)256 * 256 * 2);
    unsigned short* Wt3  = (unsigned short*)alloc((size_t)64 * 256 * 2);

    const int NB = (N_NODES + 255) / 256;
    const int EB = (ETOT + 255) / 256;
    const int WB = (N_NODES + 3) / 4;
    const int MB = (N_NODES + 127) / 128;   // 391 GEMM row-blocks

    // ---- CSR build ----
    hipMemsetAsync(deg,  0, (size_t)N_NODES * 4, stream);
    hipMemsetAsync(fill, 0, (size_t)N_NODES * 4, stream);
    k_hist<<<EB, 256, 0, stream>>>(ei, deg);
    k_scan1<<<NB, 256, 0, stream>>>(deg, start, bsum);
    k_scan2<<<1, 256, 0, stream>>>(bsum, NB);
    k_scan3<<<NB, 256, 0, stream>>>(start, bsum);
    k_scatter<<<EB, 256, 0, stream>>>(ei, start, fill, eSrc);

    // ---- casts ----
    k_cast4<<<(N_NODES * IN_CH / 4 + 255) / 256, 256, 0, stream>>>(x, xbf, N_NODES * IN_CH / 4);
    k_wt<<<(256 * IN_CH + 255) / 256, 256, 0, stream>>>(W1, Wt1, IN_CH, 256, 256);
    k_wt<<<(256 * 256 + 255) / 256, 256, 0, stream>>>(W2, Wt2, 256, 256, 256);
    k_wt<<<(64 * 256 + 255) / 256, 256, 0, stream>>>(W3, Wt3, 256, OUT_CH, 64);

    // ---- layer 1 ----
    k_mfma<128, 4, 4><<<dim3(MB, 2), 256, 0, stream>>>(xbf, Wt1, hA, N_NODES, IN_CH, 256);
    k_logits4<<<WB, 256, 0, stream>>>(hA, as1, ad1, als, ald);
    k_agg4<<<WB, 256, 0, stream>>>(hA, start, deg, eSrc, als, ald, b1, hBbf);

    // ---- layer 2 ----
    k_mfma<128, 4, 4><<<dim3(MB, 2), 256, 0, stream>>>(hBbf, Wt2, hA, N_NODES, 256, 256);
    k_logits4<<<WB, 256, 0, stream>>>(hA, as2, ad2, als, ald);
    k_agg4<<<WB, 256, 0, stream>>>(hA, start, deg, eSrc, als, ald, b2, hBbf);

    // ---- layer 3 ----
    k_mfma<64, 2, 4><<<dim3(MB, 1), 256, 0, stream>>>(hBbf, Wt3, h3, N_NODES, 256, OUT_CH);
    k_logits1<<<WB, 256, 0, stream>>>(h3, as3, ad3, als, ald);
    k_agg1<<<WB, 256, 0, stream>>>(h3, start, deg, eSrc, als, ald, b3, out);
}

// Round 3
// 592.307 us; speedup vs baseline: 1.5122x; 1.0745x over previous
//
#include <hip/hip_runtime.h>
#include <math.h>

#define N_NODES 50000
#define N_EDGES 800000
#define ETOT    (N_EDGES + N_NODES)
#define IN_CH   128
#define OUT_CH  40
#define NEG     0.2f

typedef __attribute__((ext_vector_type(8))) short bf16x8;
typedef __attribute__((ext_vector_type(4))) float f32x4;

__device__ inline unsigned short f2bf(float f) {
    unsigned int u = __float_as_uint(f);
    return (unsigned short)((u + 0x7FFFu + ((u >> 16) & 1u)) >> 16);
}
__device__ inline float bf2f(unsigned short u) {
    return __uint_as_float((unsigned int)u << 16);
}

// ---------------------------------------------------------------------------
// CSR build: histogram of dst, exclusive scan, scatter src indices
// ---------------------------------------------------------------------------
__global__ void k_hist(const int* __restrict__ ei, int* __restrict__ deg) {
    int i = blockIdx.x * blockDim.x + threadIdx.x;
    if (i >= ETOT) return;
    int d = (i < N_EDGES) ? ei[N_EDGES + i] : (i - N_EDGES);
    atomicAdd(&deg[d], 1);
}

__global__ void k_scan1(const int* __restrict__ deg, int* __restrict__ start,
                        int* __restrict__ bsum) {
    __shared__ int sh[256];
    int tid = threadIdx.x;
    int i = blockIdx.x * 256 + tid;
    int v = (i < N_NODES) ? deg[i] : 0;
    int x = v;
    sh[tid] = x;
    __syncthreads();
    #pragma unroll
    for (int off = 1; off < 256; off <<= 1) {
        int t = (tid >= off) ? sh[tid - off] : 0;
        __syncthreads();
        x += t;
        sh[tid] = x;
        __syncthreads();
    }
    if (i < N_NODES) start[i] = x - v;
    if (tid == 255) bsum[blockIdx.x] = x;
}

__global__ void k_scan2(int* __restrict__ bsum, int nb) {
    __shared__ int sh[256];
    int tid = threadIdx.x;
    int v = (tid < nb) ? bsum[tid] : 0;
    int x = v;
    sh[tid] = x;
    __syncthreads();
    #pragma unroll
    for (int off = 1; off < 256; off <<= 1) {
        int t = (tid >= off) ? sh[tid - off] : 0;
        __syncthreads();
        x += t;
        sh[tid] = x;
        __syncthreads();
    }
    if (tid < nb) bsum[tid] = x - v;
}

__global__ void k_scan3(int* __restrict__ start, const int* __restrict__ bsum) {
    int i = blockIdx.x * 256 + threadIdx.x;
    if (i < N_NODES) start[i] += bsum[blockIdx.x];
}

__global__ void k_scatter(const int* __restrict__ ei, const int* __restrict__ start,
                          int* __restrict__ fill, int* __restrict__ eSrc) {
    int i = blockIdx.x * blockDim.x + threadIdx.x;
    if (i >= ETOT) return;
    int s, d;
    if (i < N_EDGES) { s = ei[i]; d = ei[N_EDGES + i]; }
    else             { s = i - N_EDGES; d = s; }
    int pos = start[d] + atomicAdd(&fill[d], 1);
    eSrc[pos] = s;
}

// ---------------------------------------------------------------------------
// Cast helpers: fp32 -> bf16 (activations), W[K][N] fp32 -> Wt[Npad][K] bf16
// ---------------------------------------------------------------------------
__global__ void k_cast4(const float* __restrict__ in, unsigned short* __restrict__ out,
                        int n4) {
    int i = blockIdx.x * blockDim.x + threadIdx.x;
    if (i >= n4) return;
    float4 v = ((const float4*)in)[i];
    ushort4 o;
    o.x = f2bf(v.x); o.y = f2bf(v.y); o.z = f2bf(v.z); o.w = f2bf(v.w);
    ((ushort4*)out)[i] = o;
}

__global__ void k_wt(const float* __restrict__ W, unsigned short* __restrict__ Wt,
                     int K, int Ncol, int Npad) {
    int i = blockIdx.x * blockDim.x + threadIdx.x;
    if (i >= Npad * K) return;
    int n = i / K, k = i - n * K;
    Wt[n * K + k] = (n < Ncol) ? f2bf(W[(long)k * Ncol + n]) : (unsigned short)0;
}

// ---------------------------------------------------------------------------
// bf16 MFMA GEMM: C[M,Ncol] = A[M,K] @ B[K,Ncol], B pre-transposed bf16
// Bt[Npad][K]. 128 x BN block tile, 4 waves, 16x16x32 MFMA. Output bf16.
// BN=128: waves 2x2 (FM=4,FN=4).  BN=64: waves 4x1 (FM=2,FN=4).
// ---------------------------------------------------------------------------
#define PITCH 40   // bf16 elements per LDS row (32 data + 8 pad) = 80 B
template<int BN, int FM, int FN>
__global__ __launch_bounds__(256) void k_mfma(const unsigned short* __restrict__ A,
                                              const unsigned short* __restrict__ Bt,
                                              unsigned short* __restrict__ C,
                                              int M, int K, int Ncol) {
    __shared__ unsigned short As[128 * PITCH];
    __shared__ unsigned short Bs[BN * PITCH];
    const int WCOLS = BN / (FN * 16);
    int tid = threadIdx.x;
    int wave = tid >> 6, lane = tid & 63;
    int quad = lane >> 4, l16 = lane & 15;
    int wr = wave / WCOLS, wc = wave % WCOLS;
    long row0 = (long)blockIdx.x * 128;
    int col0 = blockIdx.y * BN;

    f32x4 acc[FM][FN] = {};

    for (int k0 = 0; k0 < K; k0 += 32) {
        for (int c = tid; c < 512; c += 256) {
            int r = c >> 2, kp = (c & 3) << 3;
            long gr = row0 + r;
            uint4 v = {0u, 0u, 0u, 0u};
            if (gr < M) v = *(const uint4*)(A + gr * K + k0 + kp);
            *(uint4*)(As + r * PITCH + kp) = v;
        }
        for (int c = tid; c < BN * 4; c += 256) {
            int r = c >> 2, kp = (c & 3) << 3;
            uint4 v = *(const uint4*)(Bt + (long)(col0 + r) * K + k0 + kp);
            *(uint4*)(Bs + r * PITCH + kp) = v;
        }
        __syncthreads();
        bf16x8 af[FM], bfr[FN];
        #pragma unroll
        for (int i = 0; i < FM; ++i)
            af[i] = *(const bf16x8*)(As + (wr * FM * 16 + i * 16 + l16) * PITCH + quad * 8);
        #pragma unroll
        for (int j = 0; j < FN; ++j)
            bfr[j] = *(const bf16x8*)(Bs + (wc * FN * 16 + j * 16 + l16) * PITCH + quad * 8);
        #pragma unroll
        for (int i = 0; i < FM; ++i)
            #pragma unroll
            for (int j = 0; j < FN; ++j)
                acc[i][j] = __builtin_amdgcn_mfma_f32_16x16x32_bf16(af[i], bfr[j], acc[i][j], 0, 0, 0);
        __syncthreads();
    }

    #pragma unroll
    for (int i = 0; i < FM; ++i) {
        long rowb = row0 + wr * FM * 16 + i * 16 + quad * 4;
        #pragma unroll
        for (int j = 0; j < FN; ++j) {
            int col = col0 + wc * FN * 16 + j * 16 + l16;
            if (col < Ncol) {
                #pragma unroll
                for (int v = 0; v < 4; ++v) {
                    long r = rowb + v;
                    if (r < M) C[r * Ncol + col] = f2bf(acc[i][j][v]);
                }
            }
        }
    }
}

// ---------------------------------------------------------------------------
// Attention logits (4-head layers): one wave per node, bf16 h
// ---------------------------------------------------------------------------
__global__ __launch_bounds__(256) void k_logits4(const unsigned short* __restrict__ h,
                                                 const float* __restrict__ a_s,
                                                 const float* __restrict__ a_d,
                                                 float* __restrict__ als,
                                                 float* __restrict__ ald) {
    int wave = (blockIdx.x * blockDim.x + threadIdx.x) >> 6;
    int lane = threadIdx.x & 63;
    if (wave >= N_NODES) return;
    ushort4 hu = *(const ushort4*)(h + (long)wave * 256 + lane * 4);
    float hx = bf2f(hu.x), hy = bf2f(hu.y), hz = bf2f(hu.z), hw = bf2f(hu.w);
    int head = lane >> 4;
    int cbase = (lane * 4) & 63;
    float4 sv = *(const float4*)(a_s + head * 64 + cbase);
    float4 dv = *(const float4*)(a_d + head * 64 + cbase);
    float ps = hx * sv.x + hy * sv.y + hz * sv.z + hw * sv.w;
    float pd = hx * dv.x + hy * dv.y + hz * dv.z + hw * dv.w;
    #pragma unroll
    for (int off = 1; off < 16; off <<= 1) {
        ps += __shfl_xor(ps, off);
        pd += __shfl_xor(pd, off);
    }
    if ((lane & 15) == 0) {
        als[wave * 4 + head] = ps;
        ald[wave * 4 + head] = pd;
    }
}

__global__ __launch_bounds__(256) void k_logits1(const unsigned short* __restrict__ h,
                                                 const float* __restrict__ a_s,
                                                 const float* __restrict__ a_d,
                                                 float* __restrict__ als,
                                                 float* __restrict__ ald) {
    int wave = (blockIdx.x * blockDim.x + threadIdx.x) >> 6;
    int lane = threadIdx.x & 63;
    if (wave >= N_NODES) return;
    float hv = (lane < OUT_CH) ? bf2f(h[(long)wave * OUT_CH + lane]) : 0.f;
    float ps = (lane < OUT_CH) ? hv * a_s[lane] : 0.f;
    float pd = (lane < OUT_CH) ? hv * a_d[lane] : 0.f;
    #pragma unroll
    for (int off = 1; off < 64; off <<= 1) {
        ps += __shfl_xor(ps, off);
        pd += __shfl_xor(pd, off);
    }
    if (lane == 0) {
        als[wave] = ps;
        ald[wave] = pd;
    }
}

// ---------------------------------------------------------------------------
// Aggregation + online softmax (4-head layers). bf16 gather, bf16 out.
// out = relu(agg + bias)
// ---------------------------------------------------------------------------
__global__ __launch_bounds__(256) void k_agg4(const unsigned short* __restrict__ h,
                                              const int* __restrict__ start,
                                              const int* __restrict__ deg,
                                              const int* __restrict__ eSrc,
                                              const float* __restrict__ als,
                                              const float* __restrict__ ald,
                                              const float* __restrict__ bias,
                                              unsigned short* __restrict__ out) {
    int node = (blockIdx.x * blockDim.x + threadIdx.x) >> 6;
    int lane = threadIdx.x & 63;
    if (node >= N_NODES) return;
    int st = start[node];
    int dg = deg[node];
    int head = lane >> 4;
    float aldd = ald[node * 4 + head];
    float m = -INFINITY, den = 0.f;
    float4 acc = {0.f, 0.f, 0.f, 0.f};
    for (int j = 0; j < dg; ++j) {
        int s = eSrc[st + j];
        float a = als[s * 4 + head] + aldd;
        a = (a > 0.f) ? a : NEG * a;
        float nm = fmaxf(m, a);
        float sc = __expf(m - nm);
        float w = __expf(a - nm);
        ushort4 hu = *(const ushort4*)(h + (long)s * 256 + lane * 4);
        den = den * sc + w;
        acc.x = acc.x * sc + w * bf2f(hu.x);
        acc.y = acc.y * sc + w * bf2f(hu.y);
        acc.z = acc.z * sc + w * bf2f(hu.z);
        acc.w = acc.w * sc + w * bf2f(hu.w);
        m = nm;
    }
    float inv = 1.f / den;
    int c = lane * 4;
    float4 bv = *(const float4*)(bias + c);
    ushort4 o;
    o.x = f2bf(fmaxf(acc.x * inv + bv.x, 0.f));
    o.y = f2bf(fmaxf(acc.y * inv + bv.y, 0.f));
    o.z = f2bf(fmaxf(acc.z * inv + bv.z, 0.f));
    o.w = f2bf(fmaxf(acc.w * inv + bv.w, 0.f));
    *(ushort4*)(out + (long)node * 256 + c) = o;
}

// final layer: 1 head, C=40, bf16 gather, fused bias + log_softmax (fp32 out)
__global__ __launch_bounds__(256) void k_agg1(const unsigned short* __restrict__ h,
                                              const int* __restrict__ start,
                                              const int* __restrict__ deg,
                                              const int* __restrict__ eSrc,
                                              const float* __restrict__ als,
                                              const float* __restrict__ ald,
                                              const float* __restrict__ bias,
                                              float* __restrict__ out) {
    int node = (blockIdx.x * blockDim.x + threadIdx.x) >> 6;
    int lane = threadIdx.x & 63;
    if (node >= N_NODES) return;
    int st = start[node];
    int dg = deg[node];
    float aldd = ald[node];
    float m = -INFINITY, den = 0.f, acc = 0.f;
    for (int j = 0; j < dg; ++j) {
        int s = eSrc[st + j];
        float a = als[s] + aldd;
        a = (a > 0.f) ? a : NEG * a;
        float nm = fmaxf(m, a);
        float sc = __expf(m - nm);
        float w = __expf(a - nm);
        float hv = (lane < OUT_CH) ? bf2f(h[(long)s * OUT_CH + lane]) : 0.f;
        den = den * sc + w;
        acc = acc * sc + w * hv;
        m = nm;
    }
    float v = acc / den + ((lane < OUT_CH) ? bias[lane] : 0.f);
    float vm = (lane < OUT_CH) ? v : -INFINITY;
    float mx = vm;
    #pragma unroll
    for (int off = 1; off < 64; off <<= 1) mx = fmaxf(mx, __shfl_xor(mx, off));
    float ex = (lane < OUT_CH) ? __expf(v - mx) : 0.f;
    float sum = ex;
    #pragma unroll
    for (int off = 1; off < 64; off <<= 1) sum += __shfl_xor(sum, off);
    float res = v - mx - logf(sum);
    if (lane < OUT_CH) out[(long)node * OUT_CH + lane] = res;
}

// ---------------------------------------------------------------------------
extern "C" void kernel_launch(void* const* d_in, const int* in_sizes, int n_in,
                              void* d_out, int out_size, void* d_ws, size_t ws_size,
                              hipStream_t stream) {
    (void)in_sizes; (void)n_in; (void)out_size; (void)ws_size;
    const float* x   = (const float*)d_in[0];
    const int*   ei  = (const int*)d_in[1];
    const float* W1  = (const float*)d_in[2];
    const float* as1 = (const float*)d_in[3];
    const float* ad1 = (const float*)d_in[4];
    const float* b1  = (const float*)d_in[5];
    const float* W2  = (const float*)d_in[6];
    const float* as2 = (const float*)d_in[7];
    const float* ad2 = (const float*)d_in[8];
    const float* b2  = (const float*)d_in[9];
    const float* W3  = (const float*)d_in[10];
    const float* as3 = (const float*)d_in[11];
    const float* ad3 = (const float*)d_in[12];
    const float* b3  = (const float*)d_in[13];
    float* out = (float*)d_out;

    char* p = (char*)d_ws;
    auto alloc = [&](size_t b) { char* r = p; p += (b + 255) & ~(size_t)255; return r; };
    int*   deg   = (int*)alloc((size_t)N_NODES * 4);
    int*   start = (int*)alloc((size_t)N_NODES * 4);
    int*   fill  = (int*)alloc((size_t)N_NODES * 4);
    int*   bsum  = (int*)alloc(256 * 4);
    int*   eSrc  = (int*)alloc((size_t)ETOT * 4);
    float* als   = (float*)alloc((size_t)N_NODES * 4 * 4);
    float* ald   = (float*)alloc((size_t)N_NODES * 4 * 4);
    unsigned short* xbf  = (unsigned short*)alloc((size_t)N_NODES * IN_CH * 2);
    unsigned short* hAbf = (unsigned short*)alloc((size_t)N_NODES * 256 * 2);  // GEMM out
    unsigned short* hBbf = (unsigned short*)alloc((size_t)N_NODES * 256 * 2);  // agg out
    unsigned short* h3bf = (unsigned short*)alloc((size_t)N_NODES * OUT_CH * 2);
    unsigned short* Wt1  = (unsigned short*)alloc((size_t)256 * IN_CH * 2);
    unsigned short* Wt2  = (unsigned short*)alloc((size_t)256 * 256 * 2);
    unsigned short* Wt3  = (unsigned short*)alloc((size_t)64 * 256 * 2);

    const int NB = (N_NODES + 255) / 256;
    const int EB = (ETOT + 255) / 256;
    const int WB = (N_NODES + 3) / 4;
    const int MB = (N_NODES + 127) / 128;

    // ---- CSR build ----
    hipMemsetAsync(deg,  0, (size_t)N_NODES * 4, stream);
    hipMemsetAsync(fill, 0, (size_t)N_NODES * 4, stream);
    k_hist<<<EB, 256, 0, stream>>>(ei, deg);
    k_scan1<<<NB, 256, 0, stream>>>(deg, start, bsum);
    k_scan2<<<1, 256, 0, stream>>>(bsum, NB);
    k_scan3<<<NB, 256, 0, stream>>>(start, bsum);
    k_scatter<<<EB, 256, 0, stream>>>(ei, start, fill, eSrc);

    // ---- casts ----
    k_cast4<<<(N_NODES * IN_CH / 4 + 255) / 256, 256, 0, stream>>>(x, xbf, N_NODES * IN_CH / 4);
    k_wt<<<(256 * IN_CH + 255) / 256, 256, 0, stream>>>(W1, Wt1, IN_CH, 256, 256);
    k_wt<<<(256 * 256 + 255) / 256, 256, 0, stream>>>(W2, Wt2, 256, 256, 256);
    k_wt<<<(64 * 256 + 255) / 256, 256, 0, stream>>>(W3, Wt3, 256, OUT_CH, 64);

    // ---- layer 1 ----
    k_mfma<128, 4, 4><<<dim3(MB, 2), 256, 0, stream>>>(xbf, Wt1, hAbf, N_NODES, IN_CH, 256);
    k_logits4<<<WB, 256, 0, stream>>>(hAbf, as1, ad1, als, ald);
    k_agg4<<<WB, 256, 0, stream>>>(hAbf, start, deg, eSrc, als, ald, b1, hBbf);

    // ---- layer 2 ----
    k_mfma<128, 4, 4><<<dim3(MB, 2), 256, 0, stream>>>(hBbf, Wt2, hAbf, N_NODES, 256, 256);
    k_logits4<<<WB, 256, 0, stream>>>(hAbf, as2, ad2, als, ald);
    k_agg4<<<WB, 256, 0, stream>>>(hAbf, start, deg, eSrc, als, ald, b2, hBbf);

    // ---- layer 3 ----
    k_mfma<64, 2, 4><<<dim3(MB, 1), 256, 0, stream>>>(hBbf, Wt3, h3bf, N_NODES, 256, OUT_CH);
    k_logits1<<<WB, 256, 0, stream>>>(h3bf, as3, ad3, als, ald);
    k_agg1<<<WB, 256, 0, stream>>>(h3bf, start, deg, eSrc, als, ald, b3, out);
}

// Round 4
// 575.648 us; speedup vs baseline: 1.5560x; 1.0289x over previous
//
#include <hip/hip_runtime.h>
#include <math.h>

#define N_NODES 50000
#define N_EDGES 800000
#define ETOT    (N_EDGES + N_NODES)
#define IN_CH   128
#define OUT_CH  40
#define NEG     0.2f

typedef __attribute__((ext_vector_type(8))) short bf16x8;
typedef __attribute__((ext_vector_type(4))) float f32x4;

__device__ inline unsigned short f2bf(float f) {
    unsigned int u = __float_as_uint(f);
    return (unsigned short)((u + 0x7FFFu + ((u >> 16) & 1u)) >> 16);
}
__device__ inline float bf2f(unsigned short u) {
    return __uint_as_float((unsigned int)u << 16);
}
__device__ inline float lrelu(float a) { return (a > 0.f) ? a : NEG * a; }

// ---------------------------------------------------------------------------
// CSR build: histogram of dst, exclusive scan, scatter src+dst indices
// ---------------------------------------------------------------------------
__global__ void k_hist(const int* __restrict__ ei, int* __restrict__ deg) {
    int i = blockIdx.x * blockDim.x + threadIdx.x;
    if (i >= ETOT) return;
    int d = (i < N_EDGES) ? ei[N_EDGES + i] : (i - N_EDGES);
    atomicAdd(&deg[d], 1);
}

__global__ void k_scan1(const int* __restrict__ deg, int* __restrict__ start,
                        int* __restrict__ bsum) {
    __shared__ int sh[256];
    int tid = threadIdx.x;
    int i = blockIdx.x * 256 + tid;
    int v = (i < N_NODES) ? deg[i] : 0;
    int x = v;
    sh[tid] = x;
    __syncthreads();
    #pragma unroll
    for (int off = 1; off < 256; off <<= 1) {
        int t = (tid >= off) ? sh[tid - off] : 0;
        __syncthreads();
        x += t;
        sh[tid] = x;
        __syncthreads();
    }
    if (i < N_NODES) start[i] = x - v;
    if (tid == 255) bsum[blockIdx.x] = x;
}

__global__ void k_scan2(int* __restrict__ bsum, int nb) {
    __shared__ int sh[256];
    int tid = threadIdx.x;
    int v = (tid < nb) ? bsum[tid] : 0;
    int x = v;
    sh[tid] = x;
    __syncthreads();
    #pragma unroll
    for (int off = 1; off < 256; off <<= 1) {
        int t = (tid >= off) ? sh[tid - off] : 0;
        __syncthreads();
        x += t;
        sh[tid] = x;
        __syncthreads();
    }
    if (tid < nb) bsum[tid] = x - v;
}

__global__ void k_scan3(int* __restrict__ start, const int* __restrict__ bsum) {
    int i = blockIdx.x * 256 + threadIdx.x;
    if (i < N_NODES) start[i] += bsum[blockIdx.x];
}

__global__ void k_scatter(const int* __restrict__ ei, const int* __restrict__ start,
                          int* __restrict__ fill, int* __restrict__ eSrc,
                          int* __restrict__ eDst) {
    int i = blockIdx.x * blockDim.x + threadIdx.x;
    if (i >= ETOT) return;
    int s, d;
    if (i < N_EDGES) { s = ei[i]; d = ei[N_EDGES + i]; }
    else             { s = i - N_EDGES; d = s; }
    int pos = start[d] + atomicAdd(&fill[d], 1);
    eSrc[pos] = s;
    eDst[pos] = d;
}

// ---------------------------------------------------------------------------
// Per-edge leaky logits in CSR-slot order
// ---------------------------------------------------------------------------
__global__ void k_elog4(const int* __restrict__ eSrc, const int* __restrict__ eDst,
                        const float* __restrict__ als, const float* __restrict__ ald,
                        float* __restrict__ aw) {
    int i = blockIdx.x * blockDim.x + threadIdx.x;
    if (i >= ETOT) return;
    int s = eSrc[i], d = eDst[i];
    float4 av = *(const float4*)(als + (long)s * 4);
    float4 dv = *(const float4*)(ald + (long)d * 4);
    float4 o;
    o.x = lrelu(av.x + dv.x);
    o.y = lrelu(av.y + dv.y);
    o.z = lrelu(av.z + dv.z);
    o.w = lrelu(av.w + dv.w);
    *(float4*)(aw + (long)i * 4) = o;
}

__global__ void k_elog1(const int* __restrict__ eSrc, const int* __restrict__ eDst,
                        const float* __restrict__ als, const float* __restrict__ ald,
                        float* __restrict__ aw) {
    int i = blockIdx.x * blockDim.x + threadIdx.x;
    if (i >= ETOT) return;
    aw[i] = lrelu(als[eSrc[i]] + ald[eDst[i]]);
}

// ---------------------------------------------------------------------------
// Cast helpers
// ---------------------------------------------------------------------------
__global__ void k_cast4(const float* __restrict__ in, unsigned short* __restrict__ out,
                        int n4) {
    int i = blockIdx.x * blockDim.x + threadIdx.x;
    if (i >= n4) return;
    float4 v = ((const float4*)in)[i];
    ushort4 o;
    o.x = f2bf(v.x); o.y = f2bf(v.y); o.z = f2bf(v.z); o.w = f2bf(v.w);
    ((ushort4*)out)[i] = o;
}

__global__ void k_wt(const float* __restrict__ W, unsigned short* __restrict__ Wt,
                     int K, int Ncol, int Npad) {
    int i = blockIdx.x * blockDim.x + threadIdx.x;
    if (i >= Npad * K) return;
    int n = i / K, k = i - n * K;
    Wt[n * K + k] = (n < Ncol) ? f2bf(W[(long)k * Ncol + n]) : (unsigned short)0;
}

// ---------------------------------------------------------------------------
// bf16 MFMA GEMM (unchanged from R3)
// ---------------------------------------------------------------------------
#define PITCH 40
template<int BN, int FM, int FN>
__global__ __launch_bounds__(256) void k_mfma(const unsigned short* __restrict__ A,
                                              const unsigned short* __restrict__ Bt,
                                              unsigned short* __restrict__ C,
                                              int M, int K, int Ncol) {
    __shared__ unsigned short As[128 * PITCH];
    __shared__ unsigned short Bs[BN * PITCH];
    const int WCOLS = BN / (FN * 16);
    int tid = threadIdx.x;
    int wave = tid >> 6, lane = tid & 63;
    int quad = lane >> 4, l16 = lane & 15;
    int wr = wave / WCOLS, wc = wave % WCOLS;
    long row0 = (long)blockIdx.x * 128;
    int col0 = blockIdx.y * BN;

    f32x4 acc[FM][FN] = {};

    for (int k0 = 0; k0 < K; k0 += 32) {
        for (int c = tid; c < 512; c += 256) {
            int r = c >> 2, kp = (c & 3) << 3;
            long gr = row0 + r;
            uint4 v = {0u, 0u, 0u, 0u};
            if (gr < M) v = *(const uint4*)(A + gr * K + k0 + kp);
            *(uint4*)(As + r * PITCH + kp) = v;
        }
        for (int c = tid; c < BN * 4; c += 256) {
            int r = c >> 2, kp = (c & 3) << 3;
            uint4 v = *(const uint4*)(Bt + (long)(col0 + r) * K + k0 + kp);
            *(uint4*)(Bs + r * PITCH + kp) = v;
        }
        __syncthreads();
        bf16x8 af[FM], bfr[FN];
        #pragma unroll
        for (int i = 0; i < FM; ++i)
            af[i] = *(const bf16x8*)(As + (wr * FM * 16 + i * 16 + l16) * PITCH + quad * 8);
        #pragma unroll
        for (int j = 0; j < FN; ++j)
            bfr[j] = *(const bf16x8*)(Bs + (wc * FN * 16 + j * 16 + l16) * PITCH + quad * 8);
        #pragma unroll
        for (int i = 0; i < FM; ++i)
            #pragma unroll
            for (int j = 0; j < FN; ++j)
                acc[i][j] = __builtin_amdgcn_mfma_f32_16x16x32_bf16(af[i], bfr[j], acc[i][j], 0, 0, 0);
        __syncthreads();
    }

    #pragma unroll
    for (int i = 0; i < FM; ++i) {
        long rowb = row0 + wr * FM * 16 + i * 16 + quad * 4;
        #pragma unroll
        for (int j = 0; j < FN; ++j) {
            int col = col0 + wc * FN * 16 + j * 16 + l16;
            if (col < Ncol) {
                #pragma unroll
                for (int v = 0; v < 4; ++v) {
                    long r = rowb + v;
                    if (r < M) C[r * Ncol + col] = f2bf(acc[i][j][v]);
                }
            }
        }
    }
}

// ---------------------------------------------------------------------------
// Attention logits
// ---------------------------------------------------------------------------
__global__ __launch_bounds__(256) void k_logits4(const unsigned short* __restrict__ h,
                                                 const float* __restrict__ a_s,
                                                 const float* __restrict__ a_d,
                                                 float* __restrict__ als,
                                                 float* __restrict__ ald) {
    int wave = (blockIdx.x * blockDim.x + threadIdx.x) >> 6;
    int lane = threadIdx.x & 63;
    if (wave >= N_NODES) return;
    ushort4 hu = *(const ushort4*)(h + (long)wave * 256 + lane * 4);
    float hx = bf2f(hu.x), hy = bf2f(hu.y), hz = bf2f(hu.z), hw = bf2f(hu.w);
    int head = lane >> 4;
    int cbase = (lane * 4) & 63;
    float4 sv = *(const float4*)(a_s + head * 64 + cbase);
    float4 dv = *(const float4*)(a_d + head * 64 + cbase);
    float ps = hx * sv.x + hy * sv.y + hz * sv.z + hw * sv.w;
    float pd = hx * dv.x + hy * dv.y + hz * dv.z + hw * dv.w;
    #pragma unroll
    for (int off = 1; off < 16; off <<= 1) {
        ps += __shfl_xor(ps, off);
        pd += __shfl_xor(pd, off);
    }
    if ((lane & 15) == 0) {
        als[wave * 4 + head] = ps;
        ald[wave * 4 + head] = pd;
    }
}

__global__ __launch_bounds__(256) void k_logits1(const unsigned short* __restrict__ h,
                                                 const float* __restrict__ a_s,
                                                 const float* __restrict__ a_d,
                                                 float* __restrict__ als,
                                                 float* __restrict__ ald) {
    int wave = (blockIdx.x * blockDim.x + threadIdx.x) >> 6;
    int lane = threadIdx.x & 63;
    if (wave >= N_NODES) return;
    float hv = (lane < OUT_CH) ? bf2f(h[(long)wave * OUT_CH + lane]) : 0.f;
    float ps = (lane < OUT_CH) ? hv * a_s[lane] : 0.f;
    float pd = (lane < OUT_CH) ? hv * a_d[lane] : 0.f;
    #pragma unroll
    for (int off = 1; off < 64; off <<= 1) {
        ps += __shfl_xor(ps, off);
        pd += __shfl_xor(pd, off);
    }
    if (lane == 0) {
        als[wave] = ps;
        ald[wave] = pd;
    }
}

// ---------------------------------------------------------------------------
// Aggregation: two-pass softmax over precomputed edge logits.
// Pass 1: max over aw. Pass 2: accumulate exp(a-m)*h, unrolled x2.
// ---------------------------------------------------------------------------
__global__ __launch_bounds__(256) void k_agg4(const unsigned short* __restrict__ h,
                                              const int* __restrict__ start,
                                              const int* __restrict__ deg,
                                              const int* __restrict__ eSrc,
                                              const float* __restrict__ aw,
                                              const float* __restrict__ bias,
                                              unsigned short* __restrict__ out) {
    int node = (blockIdx.x * blockDim.x + threadIdx.x) >> 6;
    int lane = threadIdx.x & 63;
    if (node >= N_NODES) return;
    int st = start[node];
    int dg = deg[node];
    int head = lane >> 4;
    const float* awp = aw + (long)st * 4 + head;
    const int* ep = eSrc + st;

    float m = -INFINITY;
    for (int j = 0; j < dg; ++j) m = fmaxf(m, awp[j * 4]);

    float den = 0.f;
    float4 acc = {0.f, 0.f, 0.f, 0.f};
    int j = 0;
    for (; j + 1 < dg; j += 2) {
        int s0 = ep[j], s1 = ep[j + 1];
        float a0 = awp[j * 4], a1 = awp[(j + 1) * 4];
        ushort4 h0 = *(const ushort4*)(h + (long)s0 * 256 + lane * 4);
        ushort4 h1 = *(const ushort4*)(h + (long)s1 * 256 + lane * 4);
        float w0 = __expf(a0 - m), w1 = __expf(a1 - m);
        den += w0 + w1;
        acc.x += w0 * bf2f(h0.x) + w1 * bf2f(h1.x);
        acc.y += w0 * bf2f(h0.y) + w1 * bf2f(h1.y);
        acc.z += w0 * bf2f(h0.z) + w1 * bf2f(h1.z);
        acc.w += w0 * bf2f(h0.w) + w1 * bf2f(h1.w);
    }
    if (j < dg) {
        int s0 = ep[j];
        float w0 = __expf(awp[j * 4] - m);
        ushort4 h0 = *(const ushort4*)(h + (long)s0 * 256 + lane * 4);
        den += w0;
        acc.x += w0 * bf2f(h0.x);
        acc.y += w0 * bf2f(h0.y);
        acc.z += w0 * bf2f(h0.z);
        acc.w += w0 * bf2f(h0.w);
    }
    float inv = 1.f / den;
    int c = lane * 4;
    float4 bv = *(const float4*)(bias + c);
    ushort4 o;
    o.x = f2bf(fmaxf(acc.x * inv + bv.x, 0.f));
    o.y = f2bf(fmaxf(acc.y * inv + bv.y, 0.f));
    o.z = f2bf(fmaxf(acc.z * inv + bv.z, 0.f));
    o.w = f2bf(fmaxf(acc.w * inv + bv.w, 0.f));
    *(ushort4*)(out + (long)node * 256 + c) = o;
}

// final layer: 1 head, C=40, fused bias + log_softmax (fp32 out)
__global__ __launch_bounds__(256) void k_agg1(const unsigned short* __restrict__ h,
                                              const int* __restrict__ start,
                                              const int* __restrict__ deg,
                                              const int* __restrict__ eSrc,
                                              const float* __restrict__ aw,
                                              const float* __restrict__ bias,
                                              float* __restrict__ out) {
    int node = (blockIdx.x * blockDim.x + threadIdx.x) >> 6;
    int lane = threadIdx.x & 63;
    if (node >= N_NODES) return;
    int st = start[node];
    int dg = deg[node];
    const float* awp = aw + st;
    const int* ep = eSrc + st;

    float m = -INFINITY;
    for (int j = 0; j < dg; ++j) m = fmaxf(m, awp[j]);

    float den = 0.f, acc = 0.f;
    int j = 0;
    for (; j + 1 < dg; j += 2) {
        int s0 = ep[j], s1 = ep[j + 1];
        float w0 = __expf(awp[j] - m), w1 = __expf(awp[j + 1] - m);
        float h0 = (lane < OUT_CH) ? bf2f(h[(long)s0 * OUT_CH + lane]) : 0.f;
        float h1 = (lane < OUT_CH) ? bf2f(h[(long)s1 * OUT_CH + lane]) : 0.f;
        den += w0 + w1;
        acc += w0 * h0 + w1 * h1;
    }
    if (j < dg) {
        int s0 = ep[j];
        float w0 = __expf(awp[j] - m);
        float h0 = (lane < OUT_CH) ? bf2f(h[(long)s0 * OUT_CH + lane]) : 0.f;
        den += w0;
        acc += w0 * h0;
    }
    float v = acc / den + ((lane < OUT_CH) ? bias[lane] : 0.f);
    float vm = (lane < OUT_CH) ? v : -INFINITY;
    float mx = vm;
    #pragma unroll
    for (int off = 1; off < 64; off <<= 1) mx = fmaxf(mx, __shfl_xor(mx, off));
    float ex = (lane < OUT_CH) ? __expf(v - mx) : 0.f;
    float sum = ex;
    #pragma unroll
    for (int off = 1; off < 64; off <<= 1) sum += __shfl_xor(sum, off);
    float res = v - mx - logf(sum);
    if (lane < OUT_CH) out[(long)node * OUT_CH + lane] = res;
}

// ---------------------------------------------------------------------------
extern "C" void kernel_launch(void* const* d_in, const int* in_sizes, int n_in,
                              void* d_out, int out_size, void* d_ws, size_t ws_size,
                              hipStream_t stream) {
    (void)in_sizes; (void)n_in; (void)out_size; (void)ws_size;
    const float* x   = (const float*)d_in[0];
    const int*   ei  = (const int*)d_in[1];
    const float* W1  = (const float*)d_in[2];
    const float* as1 = (const float*)d_in[3];
    const float* ad1 = (const float*)d_in[4];
    const float* b1  = (const float*)d_in[5];
    const float* W2  = (const float*)d_in[6];
    const float* as2 = (const float*)d_in[7];
    const float* ad2 = (const float*)d_in[8];
    const float* b2  = (const float*)d_in[9];
    const float* W3  = (const float*)d_in[10];
    const float* as3 = (const float*)d_in[11];
    const float* ad3 = (const float*)d_in[12];
    const float* b3  = (const float*)d_in[13];
    float* out = (float*)d_out;

    char* p = (char*)d_ws;
    auto alloc = [&](size_t b) { char* r = p; p += (b + 255) & ~(size_t)255; return r; };
    int*   deg   = (int*)alloc((size_t)N_NODES * 4);
    int*   start = (int*)alloc((size_t)N_NODES * 4);
    int*   fill  = (int*)alloc((size_t)N_NODES * 4);
    int*   bsum  = (int*)alloc(256 * 4);
    int*   eSrc  = (int*)alloc((size_t)ETOT * 4);
    int*   eDst  = (int*)alloc((size_t)ETOT * 4);
    float* aw    = (float*)alloc((size_t)ETOT * 4 * 4);
    float* als   = (float*)alloc((size_t)N_NODES * 4 * 4);
    float* ald   = (float*)alloc((size_t)N_NODES * 4 * 4);
    unsigned short* xbf  = (unsigned short*)alloc((size_t)N_NODES * IN_CH * 2);
    unsigned short* hAbf = (unsigned short*)alloc((size_t)N_NODES * 256 * 2);
    unsigned short* hBbf = (unsigned short*)alloc((size_t)N_NODES * 256 * 2);
    unsigned short* h3bf = (unsigned short*)alloc((size_t)N_NODES * OUT_CH * 2);
    unsigned short* Wt1  = (unsigned short*)alloc((size_t)256 * IN_CH * 2);
    unsigned short* Wt2  = (unsigned short*)alloc((size_t)256 * 256 * 2);
    unsigned short* Wt3  = (unsigned short*)alloc((size_t)64 * 256 * 2);

    const int NB = (N_NODES + 255) / 256;
    const int EB = (ETOT + 255) / 256;
    const int WB = (N_NODES + 3) / 4;
    const int MB = (N_NODES + 127) / 128;

    // ---- CSR build ----
    hipMemsetAsync(deg,  0, (size_t)N_NODES * 4, stream);
    hipMemsetAsync(fill, 0, (size_t)N_NODES * 4, stream);
    k_hist<<<EB, 256, 0, stream>>>(ei, deg);
    k_scan1<<<NB, 256, 0, stream>>>(deg, start, bsum);
    k_scan2<<<1, 256, 0, stream>>>(bsum, NB);
    k_scan3<<<NB, 256, 0, stream>>>(start, bsum);
    k_scatter<<<EB, 256, 0, stream>>>(ei, start, fill, eSrc, eDst);

    // ---- casts ----
    k_cast4<<<(N_NODES * IN_CH / 4 + 255) / 256, 256, 0, stream>>>(x, xbf, N_NODES * IN_CH / 4);
    k_wt<<<(256 * IN_CH + 255) / 256, 256, 0, stream>>>(W1, Wt1, IN_CH, 256, 256);
    k_wt<<<(256 * 256 + 255) / 256, 256, 0, stream>>>(W2, Wt2, 256, 256, 256);
    k_wt<<<(64 * 256 + 255) / 256, 256, 0, stream>>>(W3, Wt3, 256, OUT_CH, 64);

    // ---- layer 1 ----
    k_mfma<128, 4, 4><<<dim3(MB, 2), 256, 0, stream>>>(xbf, Wt1, hAbf, N_NODES, IN_CH, 256);
    k_logits4<<<WB, 256, 0, stream>>>(hAbf, as1, ad1, als, ald);
    k_elog4<<<EB, 256, 0, stream>>>(eSrc, eDst, als, ald, aw);
    k_agg4<<<WB, 256, 0, stream>>>(hAbf, start, deg, eSrc, aw, b1, hBbf);

    // ---- layer 2 ----
    k_mfma<128, 4, 4><<<dim3(MB, 2), 256, 0, stream>>>(hBbf, Wt2, hAbf, N_NODES, 256, 256);
    k_logits4<<<WB, 256, 0, stream>>>(hAbf, as2, ad2, als, ald);
    k_elog4<<<EB, 256, 0, stream>>>(eSrc, eDst, als, ald, aw);
    k_agg4<<<WB, 256, 0, stream>>>(hAbf, start, deg, eSrc, aw, b2, hBbf);

    // ---- layer 3 ----
    k_mfma<64, 2, 4><<<dim3(MB, 1), 256, 0, stream>>>(hBbf, Wt3, h3bf, N_NODES, 256, OUT_CH);
    k_logits1<<<WB, 256, 0, stream>>>(h3bf, as3, ad3, als, ald);
    k_elog1<<<EB, 256, 0, stream>>>(eSrc, eDst, als, ald, aw);
    k_agg1<<<WB, 256, 0, stream>>>(h3bf, start, deg, eSrc, aw, b3, out);
}

// Round 5
// 524.837 us; speedup vs baseline: 1.7066x; 1.0968x over previous
//
#include <hip/hip_runtime.h>
#include <math.h>

#define N_NODES 50000
#define N_EDGES 800000
#define ETOT    (N_EDGES + N_NODES)
#define EPAD_MAX 1200000   // >= sum of per-node degrees rounded up to mult of 8
#define IN_CH   128
#define OUT_CH  40
#define NEG     0.2f

typedef __attribute__((ext_vector_type(8))) short bf16x8;
typedef __attribute__((ext_vector_type(4))) float f32x4;

__device__ inline unsigned short f2bf(float f) {
    unsigned int u = __float_as_uint(f);
    return (unsigned short)((u + 0x7FFFu + ((u >> 16) & 1u)) >> 16);
}
__device__ inline float bf2f(unsigned short u) {
    return __uint_as_float((unsigned int)u << 16);
}
__device__ inline float lrelu(float a) { return (a > 0.f) ? a : NEG * a; }

// ---------------------------------------------------------------------------
// CSR build: histogram of dst, exclusive scan over PADDED degrees, scatter
// ---------------------------------------------------------------------------
__global__ void k_hist(const int* __restrict__ ei, int* __restrict__ deg) {
    int i = blockIdx.x * blockDim.x + threadIdx.x;
    if (i >= ETOT) return;
    int d = (i < N_EDGES) ? ei[N_EDGES + i] : (i - N_EDGES);
    atomicAdd(&deg[d], 1);
}

__global__ void k_scan1(const int* __restrict__ deg, int* __restrict__ start,
                        int* __restrict__ bsum) {
    __shared__ int sh[256];
    int tid = threadIdx.x;
    int i = blockIdx.x * 256 + tid;
    int v = (i < N_NODES) ? ((deg[i] + 7) & ~7) : 0;   // padded degree
    int x = v;
    sh[tid] = x;
    __syncthreads();
    #pragma unroll
    for (int off = 1; off < 256; off <<= 1) {
        int t = (tid >= off) ? sh[tid - off] : 0;
        __syncthreads();
        x += t;
        sh[tid] = x;
        __syncthreads();
    }
    if (i < N_NODES) start[i] = x - v;
    if (tid == 255) bsum[blockIdx.x] = x;
}

__global__ void k_scan2(int* __restrict__ bsum, int nb) {
    __shared__ int sh[256];
    int tid = threadIdx.x;
    int v = (tid < nb) ? bsum[tid] : 0;
    int x = v;
    sh[tid] = x;
    __syncthreads();
    #pragma unroll
    for (int off = 1; off < 256; off <<= 1) {
        int t = (tid >= off) ? sh[tid - off] : 0;
        __syncthreads();
        x += t;
        sh[tid] = x;
        __syncthreads();
    }
    if (tid < nb) bsum[tid] = x - v;
}

__global__ void k_scan3(int* __restrict__ start, const int* __restrict__ bsum) {
    int i = blockIdx.x * 256 + threadIdx.x;
    if (i < N_NODES) start[i] += bsum[blockIdx.x];
}

__global__ void k_scatter(const int* __restrict__ ei, const int* __restrict__ start,
                          int* __restrict__ fill, int* __restrict__ eSrc,
                          int* __restrict__ eDst) {
    int i = blockIdx.x * blockDim.x + threadIdx.x;
    if (i >= ETOT) return;
    int s, d;
    if (i < N_EDGES) { s = ei[i]; d = ei[N_EDGES + i]; }
    else             { s = i - N_EDGES; d = s; }
    int pos = start[d] + atomicAdd(&fill[d], 1);
    eSrc[pos] = s;
    eDst[pos] = d;
}

// ---------------------------------------------------------------------------
// Per-edge softmax weights (no max shift: |logit| <~10, exp safe in fp32).
// Pad slots (eSrc=-1) are skipped; their aw stays 0 from the launch memset.
// ---------------------------------------------------------------------------
__global__ void k_ew4(const int* __restrict__ eSrc, const int* __restrict__ eDst,
                      const float* __restrict__ als, const float* __restrict__ ald,
                      float* __restrict__ aw) {
    int i = blockIdx.x * blockDim.x + threadIdx.x;
    if (i >= EPAD_MAX) return;
    int s = eSrc[i];
    if (s < 0) return;
    int d = eDst[i];
    float4 av = *(const float4*)(als + (long)s * 4);
    float4 dv = *(const float4*)(ald + (long)d * 4);
    float4 o;
    o.x = __expf(lrelu(av.x + dv.x));
    o.y = __expf(lrelu(av.y + dv.y));
    o.z = __expf(lrelu(av.z + dv.z));
    o.w = __expf(lrelu(av.w + dv.w));
    *(float4*)(aw + (long)i * 4) = o;
}

__global__ void k_ew1(const int* __restrict__ eSrc, const int* __restrict__ eDst,
                      const float* __restrict__ als, const float* __restrict__ ald,
                      float* __restrict__ aw) {
    int i = blockIdx.x * blockDim.x + threadIdx.x;
    if (i >= EPAD_MAX) return;
    int s = eSrc[i];
    if (s < 0) return;
    aw[i] = __expf(lrelu(als[s] + ald[eDst[i]]));
}

// ---------------------------------------------------------------------------
// Cast helpers
// ---------------------------------------------------------------------------
__global__ void k_cast4(const float* __restrict__ in, unsigned short* __restrict__ out,
                        int n4) {
    int i = blockIdx.x * blockDim.x + threadIdx.x;
    if (i >= n4) return;
    float4 v = ((const float4*)in)[i];
    ushort4 o;
    o.x = f2bf(v.x); o.y = f2bf(v.y); o.z = f2bf(v.z); o.w = f2bf(v.w);
    ((ushort4*)out)[i] = o;
}

__global__ void k_wt(const float* __restrict__ W, unsigned short* __restrict__ Wt,
                     int K, int Ncol, int Npad) {
    int i = blockIdx.x * blockDim.x + threadIdx.x;
    if (i >= Npad * K) return;
    int n = i / K, k = i - n * K;
    Wt[n * K + k] = (n < Ncol) ? f2bf(W[(long)k * Ncol + n]) : (unsigned short)0;
}

// ---------------------------------------------------------------------------
// bf16 MFMA GEMM (unchanged)
// ---------------------------------------------------------------------------
#define PITCH 40
template<int BN, int FM, int FN>
__global__ __launch_bounds__(256) void k_mfma(const unsigned short* __restrict__ A,
                                              const unsigned short* __restrict__ Bt,
                                              unsigned short* __restrict__ C,
                                              int M, int K, int Ncol) {
    __shared__ unsigned short As[128 * PITCH];
    __shared__ unsigned short Bs[BN * PITCH];
    const int WCOLS = BN / (FN * 16);
    int tid = threadIdx.x;
    int wave = tid >> 6, lane = tid & 63;
    int quad = lane >> 4, l16 = lane & 15;
    int wr = wave / WCOLS, wc = wave % WCOLS;
    long row0 = (long)blockIdx.x * 128;
    int col0 = blockIdx.y * BN;

    f32x4 acc[FM][FN] = {};

    for (int k0 = 0; k0 < K; k0 += 32) {
        for (int c = tid; c < 512; c += 256) {
            int r = c >> 2, kp = (c & 3) << 3;
            long gr = row0 + r;
            uint4 v = {0u, 0u, 0u, 0u};
            if (gr < M) v = *(const uint4*)(A + gr * K + k0 + kp);
            *(uint4*)(As + r * PITCH + kp) = v;
        }
        for (int c = tid; c < BN * 4; c += 256) {
            int r = c >> 2, kp = (c & 3) << 3;
            uint4 v = *(const uint4*)(Bt + (long)(col0 + r) * K + k0 + kp);
            *(uint4*)(Bs + r * PITCH + kp) = v;
        }
        __syncthreads();
        bf16x8 af[FM], bfr[FN];
        #pragma unroll
        for (int i = 0; i < FM; ++i)
            af[i] = *(const bf16x8*)(As + (wr * FM * 16 + i * 16 + l16) * PITCH + quad * 8);
        #pragma unroll
        for (int j = 0; j < FN; ++j)
            bfr[j] = *(const bf16x8*)(Bs + (wc * FN * 16 + j * 16 + l16) * PITCH + quad * 8);
        #pragma unroll
        for (int i = 0; i < FM; ++i)
            #pragma unroll
            for (int j = 0; j < FN; ++j)
                acc[i][j] = __builtin_amdgcn_mfma_f32_16x16x32_bf16(af[i], bfr[j], acc[i][j], 0, 0, 0);
        __syncthreads();
    }

    #pragma unroll
    for (int i = 0; i < FM; ++i) {
        long rowb = row0 + wr * FM * 16 + i * 16 + quad * 4;
        #pragma unroll
        for (int j = 0; j < FN; ++j) {
            int col = col0 + wc * FN * 16 + j * 16 + l16;
            if (col < Ncol) {
                #pragma unroll
                for (int v = 0; v < 4; ++v) {
                    long r = rowb + v;
                    if (r < M) C[r * Ncol + col] = f2bf(acc[i][j][v]);
                }
            }
        }
    }
}

// ---------------------------------------------------------------------------
// Attention logits
// ---------------------------------------------------------------------------
__global__ __launch_bounds__(256) void k_logits4(const unsigned short* __restrict__ h,
                                                 const float* __restrict__ a_s,
                                                 const float* __restrict__ a_d,
                                                 float* __restrict__ als,
                                                 float* __restrict__ ald) {
    int wave = (blockIdx.x * blockDim.x + threadIdx.x) >> 6;
    int lane = threadIdx.x & 63;
    if (wave >= N_NODES) return;
    ushort4 hu = *(const ushort4*)(h + (long)wave * 256 + lane * 4);
    float hx = bf2f(hu.x), hy = bf2f(hu.y), hz = bf2f(hu.z), hw = bf2f(hu.w);
    int head = lane >> 4;
    int cbase = (lane * 4) & 63;
    float4 sv = *(const float4*)(a_s + head * 64 + cbase);
    float4 dv = *(const float4*)(a_d + head * 64 + cbase);
    float ps = hx * sv.x + hy * sv.y + hz * sv.z + hw * sv.w;
    float pd = hx * dv.x + hy * dv.y + hz * dv.z + hw * dv.w;
    #pragma unroll
    for (int off = 1; off < 16; off <<= 1) {
        ps += __shfl_xor(ps, off);
        pd += __shfl_xor(pd, off);
    }
    if ((lane & 15) == 0) {
        als[wave * 4 + head] = ps;
        ald[wave * 4 + head] = pd;
    }
}

__global__ __launch_bounds__(256) void k_logits1(const unsigned short* __restrict__ h,
                                                 const float* __restrict__ a_s,
                                                 const float* __restrict__ a_d,
                                                 float* __restrict__ als,
                                                 float* __restrict__ ald) {
    int wave = (blockIdx.x * blockDim.x + threadIdx.x) >> 6;
    int lane = threadIdx.x & 63;
    if (wave >= N_NODES) return;
    float hv = (lane < OUT_CH) ? bf2f(h[(long)wave * OUT_CH + lane]) : 0.f;
    float ps = (lane < OUT_CH) ? hv * a_s[lane] : 0.f;
    float pd = (lane < OUT_CH) ? hv * a_d[lane] : 0.f;
    #pragma unroll
    for (int off = 1; off < 64; off <<= 1) {
        ps += __shfl_xor(ps, off);
        pd += __shfl_xor(pd, off);
    }
    if (lane == 0) {
        als[wave] = ps;
        ald[wave] = pd;
    }
}

// ---------------------------------------------------------------------------
// Aggregation: branch-free x8-unrolled gather-FMA over padded CSR.
// w precomputed (pads w=0). den summed in-loop. out = relu(acc/den + bias), bf16.
// ---------------------------------------------------------------------------
__global__ __launch_bounds__(256) void k_agg4(const unsigned short* __restrict__ h,
                                              const int* __restrict__ start,
                                              const int* __restrict__ deg,
                                              const int* __restrict__ eSrc,
                                              const float* __restrict__ aw,
                                              const float* __restrict__ bias,
                                              unsigned short* __restrict__ out) {
    int node = (blockIdx.x * blockDim.x + threadIdx.x) >> 6;
    int lane = threadIdx.x & 63;
    if (node >= N_NODES) return;
    int st = start[node];
    int dgp = (deg[node] + 7) & ~7;
    int head = lane >> 4;
    const float* awp = aw + (long)st * 4 + head;
    const int* ep = eSrc + st;

    float den = 0.f;
    float4 acc = {0.f, 0.f, 0.f, 0.f};
    for (int j = 0; j < dgp; j += 8) {
        int s[8];
        float w[8];
        #pragma unroll
        for (int u = 0; u < 8; ++u) s[u] = ep[j + u];
        #pragma unroll
        for (int u = 0; u < 8; ++u) w[u] = awp[(j + u) * 4];
        ushort4 hh[8];
        #pragma unroll
        for (int u = 0; u < 8; ++u) {
            int ss = (s[u] < 0) ? 0 : s[u];
            hh[u] = *(const ushort4*)(h + (long)ss * 256 + lane * 4);
        }
        #pragma unroll
        for (int u = 0; u < 8; ++u) {
            den += w[u];
            acc.x += w[u] * bf2f(hh[u].x);
            acc.y += w[u] * bf2f(hh[u].y);
            acc.z += w[u] * bf2f(hh[u].z);
            acc.w += w[u] * bf2f(hh[u].w);
        }
    }
    float inv = 1.f / den;
    int c = lane * 4;
    float4 bv = *(const float4*)(bias + c);
    ushort4 o;
    o.x = f2bf(fmaxf(acc.x * inv + bv.x, 0.f));
    o.y = f2bf(fmaxf(acc.y * inv + bv.y, 0.f));
    o.z = f2bf(fmaxf(acc.z * inv + bv.z, 0.f));
    o.w = f2bf(fmaxf(acc.w * inv + bv.w, 0.f));
    *(ushort4*)(out + (long)node * 256 + c) = o;
}

// final layer: 1 head, C=40, fused bias + log_softmax (fp32 out)
__global__ __launch_bounds__(256) void k_agg1(const unsigned short* __restrict__ h,
                                              const int* __restrict__ start,
                                              const int* __restrict__ deg,
                                              const int* __restrict__ eSrc,
                                              const float* __restrict__ aw,
                                              const float* __restrict__ bias,
                                              float* __restrict__ out) {
    int node = (blockIdx.x * blockDim.x + threadIdx.x) >> 6;
    int lane = threadIdx.x & 63;
    if (node >= N_NODES) return;
    int st = start[node];
    int dgp = (deg[node] + 7) & ~7;
    const float* awp = aw + st;
    const int* ep = eSrc + st;

    float den = 0.f, acc = 0.f;
    for (int j = 0; j < dgp; j += 8) {
        int s[8];
        float w[8];
        #pragma unroll
        for (int u = 0; u < 8; ++u) s[u] = ep[j + u];
        #pragma unroll
        for (int u = 0; u < 8; ++u) w[u] = awp[j + u];
        float hv[8];
        #pragma unroll
        for (int u = 0; u < 8; ++u) {
            int ss = (s[u] < 0) ? 0 : s[u];
            hv[u] = (lane < OUT_CH) ? bf2f(h[(long)ss * OUT_CH + lane]) : 0.f;
        }
        #pragma unroll
        for (int u = 0; u < 8; ++u) {
            den += w[u];
            acc += w[u] * hv[u];
        }
    }
    float v = acc / den + ((lane < OUT_CH) ? bias[lane] : 0.f);
    float vm = (lane < OUT_CH) ? v : -INFINITY;
    float mx = vm;
    #pragma unroll
    for (int off = 1; off < 64; off <<= 1) mx = fmaxf(mx, __shfl_xor(mx, off));
    float ex = (lane < OUT_CH) ? __expf(v - mx) : 0.f;
    float sum = ex;
    #pragma unroll
    for (int off = 1; off < 64; off <<= 1) sum += __shfl_xor(sum, off);
    float res = v - mx - logf(sum);
    if (lane < OUT_CH) out[(long)node * OUT_CH + lane] = res;
}

// ---------------------------------------------------------------------------
extern "C" void kernel_launch(void* const* d_in, const int* in_sizes, int n_in,
                              void* d_out, int out_size, void* d_ws, size_t ws_size,
                              hipStream_t stream) {
    (void)in_sizes; (void)n_in; (void)out_size; (void)ws_size;
    const float* x   = (const float*)d_in[0];
    const int*   ei  = (const int*)d_in[1];
    const float* W1  = (const float*)d_in[2];
    const float* as1 = (const float*)d_in[3];
    const float* ad1 = (const float*)d_in[4];
    const float* b1  = (const float*)d_in[5];
    const float* W2  = (const float*)d_in[6];
    const float* as2 = (const float*)d_in[7];
    const float* ad2 = (const float*)d_in[8];
    const float* b2  = (const float*)d_in[9];
    const float* W3  = (const float*)d_in[10];
    const float* as3 = (const float*)d_in[11];
    const float* ad3 = (const float*)d_in[12];
    const float* b3  = (const float*)d_in[13];
    float* out = (float*)d_out;

    char* p = (char*)d_ws;
    auto alloc = [&](size_t b) { char* r = p; p += (b + 255) & ~(size_t)255; return r; };
    int*   deg   = (int*)alloc((size_t)N_NODES * 4);
    int*   start = (int*)alloc((size_t)N_NODES * 4);
    int*   fill  = (int*)alloc((size_t)N_NODES * 4);
    int*   bsum  = (int*)alloc(256 * 4);
    int*   eSrc  = (int*)alloc((size_t)EPAD_MAX * 4);
    int*   eDst  = (int*)alloc((size_t)EPAD_MAX * 4);
    float* aw4   = (float*)alloc((size_t)EPAD_MAX * 4 * 4);
    float* aw1   = (float*)alloc((size_t)EPAD_MAX * 4);
    float* als   = (float*)alloc((size_t)N_NODES * 4 * 4);
    float* ald   = (float*)alloc((size_t)N_NODES * 4 * 4);
    unsigned short* xbf  = (unsigned short*)alloc((size_t)N_NODES * IN_CH * 2);
    unsigned short* hAbf = (unsigned short*)alloc((size_t)N_NODES * 256 * 2);
    unsigned short* hBbf = (unsigned short*)alloc((size_t)N_NODES * 256 * 2);
    unsigned short* h3bf = (unsigned short*)alloc((size_t)N_NODES * OUT_CH * 2);
    unsigned short* Wt1  = (unsigned short*)alloc((size_t)256 * IN_CH * 2);
    unsigned short* Wt2  = (unsigned short*)alloc((size_t)256 * 256 * 2);
    unsigned short* Wt3  = (unsigned short*)alloc((size_t)64 * 256 * 2);

    const int NB = (N_NODES + 255) / 256;
    const int EB = (ETOT + 255) / 256;
    const int PB = (EPAD_MAX + 255) / 256;
    const int WB = (N_NODES + 3) / 4;
    const int MB = (N_NODES + 127) / 128;

    // ---- CSR build (padded to multiple of 8 per node) ----
    hipMemsetAsync(deg,  0, (size_t)N_NODES * 4, stream);
    hipMemsetAsync(fill, 0, (size_t)N_NODES * 4, stream);
    hipMemsetAsync(eSrc, 0xFF, (size_t)EPAD_MAX * 4, stream);   // pads -> -1
    hipMemsetAsync(aw4,  0, (size_t)EPAD_MAX * 4 * 4, stream);  // pad weights 0
    hipMemsetAsync(aw1,  0, (size_t)EPAD_MAX * 4, stream);
    k_hist<<<EB, 256, 0, stream>>>(ei, deg);
    k_scan1<<<NB, 256, 0, stream>>>(deg, start, bsum);
    k_scan2<<<1, 256, 0, stream>>>(bsum, NB);
    k_scan3<<<NB, 256, 0, stream>>>(start, bsum);
    k_scatter<<<EB, 256, 0, stream>>>(ei, start, fill, eSrc, eDst);

    // ---- casts ----
    k_cast4<<<(N_NODES * IN_CH / 4 + 255) / 256, 256, 0, stream>>>(x, xbf, N_NODES * IN_CH / 4);
    k_wt<<<(256 * IN_CH + 255) / 256, 256, 0, stream>>>(W1, Wt1, IN_CH, 256, 256);
    k_wt<<<(256 * 256 + 255) / 256, 256, 0, stream>>>(W2, Wt2, 256, 256, 256);
    k_wt<<<(64 * 256 + 255) / 256, 256, 0, stream>>>(W3, Wt3, 256, OUT_CH, 64);

    // ---- layer 1 ----
    k_mfma<128, 4, 4><<<dim3(MB, 2), 256, 0, stream>>>(xbf, Wt1, hAbf, N_NODES, IN_CH, 256);
    k_logits4<<<WB, 256, 0, stream>>>(hAbf, as1, ad1, als, ald);
    k_ew4<<<PB, 256, 0, stream>>>(eSrc, eDst, als, ald, aw4);
    k_agg4<<<WB, 256, 0, stream>>>(hAbf, start, deg, eSrc, aw4, b1, hBbf);

    // ---- layer 2 ----
    k_mfma<128, 4, 4><<<dim3(MB, 2), 256, 0, stream>>>(hBbf, Wt2, hAbf, N_NODES, 256, 256);
    k_logits4<<<WB, 256, 0, stream>>>(hAbf, as2, ad2, als, ald);
    k_ew4<<<PB, 256, 0, stream>>>(eSrc, eDst, als, ald, aw4);
    k_agg4<<<WB, 256, 0, stream>>>(hAbf, start, deg, eSrc, aw4, b2, hBbf);

    // ---- layer 3 ----
    k_mfma<64, 2, 4><<<dim3(MB, 1), 256, 0, stream>>>(hBbf, Wt3, h3bf, N_NODES, 256, OUT_CH);
    k_logits1<<<WB, 256, 0, stream>>>(h3bf, as3, ad3, als, ald);
    k_ew1<<<PB, 256, 0, stream>>>(eSrc, eDst, als, ald, aw1);
    k_agg1<<<WB, 256, 0, stream>>>(h3bf, start, deg, eSrc, aw1, b3, out);
}

// Round 6
// 494.185 us; speedup vs baseline: 1.8125x; 1.0620x over previous
//
#include <hip/hip_runtime.h>
#include <math.h>

#define N_NODES 50000
#define N_EDGES 800000
#define ETOT    (N_EDGES + N_NODES)
#define EPAD_MAX 1650000   // >= sum of per-node degrees rounded up to mult of 16
#define IN_CH   128
#define OUT_CH  40
#define NEG     0.2f

typedef __attribute__((ext_vector_type(8))) short bf16x8;
typedef __attribute__((ext_vector_type(4))) float f32x4;

__device__ inline unsigned short f2bf(float f) {
    unsigned int u = __float_as_uint(f);
    return (unsigned short)((u + 0x7FFFu + ((u >> 16) & 1u)) >> 16);
}
__device__ inline float bf2f(unsigned short u) {
    return __uint_as_float((unsigned int)u << 16);
}
__device__ inline float lrelu(float a) { return (a > 0.f) ? a : NEG * a; }

// ---------------------------------------------------------------------------
// CSR build: histogram of dst, exclusive scan over degrees padded to 16, scatter
// ---------------------------------------------------------------------------
__global__ void k_hist(const int* __restrict__ ei, int* __restrict__ deg) {
    int i = blockIdx.x * blockDim.x + threadIdx.x;
    if (i >= ETOT) return;
    int d = (i < N_EDGES) ? ei[N_EDGES + i] : (i - N_EDGES);
    atomicAdd(&deg[d], 1);
}

__global__ void k_scan1(const int* __restrict__ deg, int* __restrict__ start,
                        int* __restrict__ bsum) {
    __shared__ int sh[256];
    int tid = threadIdx.x;
    int i = blockIdx.x * 256 + tid;
    int v = (i < N_NODES) ? ((deg[i] + 15) & ~15) : 0;   // padded degree
    int x = v;
    sh[tid] = x;
    __syncthreads();
    #pragma unroll
    for (int off = 1; off < 256; off <<= 1) {
        int t = (tid >= off) ? sh[tid - off] : 0;
        __syncthreads();
        x += t;
        sh[tid] = x;
        __syncthreads();
    }
    if (i < N_NODES) start[i] = x - v;
    if (tid == 255) bsum[blockIdx.x] = x;
}

__global__ void k_scan2(int* __restrict__ bsum, int nb) {
    __shared__ int sh[256];
    int tid = threadIdx.x;
    int v = (tid < nb) ? bsum[tid] : 0;
    int x = v;
    sh[tid] = x;
    __syncthreads();
    #pragma unroll
    for (int off = 1; off < 256; off <<= 1) {
        int t = (tid >= off) ? sh[tid - off] : 0;
        __syncthreads();
        x += t;
        sh[tid] = x;
        __syncthreads();
    }
    if (tid < nb) bsum[tid] = x - v;
}

__global__ void k_scan3(int* __restrict__ start, const int* __restrict__ bsum) {
    int i = blockIdx.x * 256 + threadIdx.x;
    if (i < N_NODES) start[i] += bsum[blockIdx.x];
}

__global__ void k_scatter(const int* __restrict__ ei, const int* __restrict__ start,
                          int* __restrict__ fill, int* __restrict__ eSrc,
                          int* __restrict__ eDst) {
    int i = blockIdx.x * blockDim.x + threadIdx.x;
    if (i >= ETOT) return;
    int s, d;
    if (i < N_EDGES) { s = ei[i]; d = ei[N_EDGES + i]; }
    else             { s = i - N_EDGES; d = s; }
    int pos = start[d] + atomicAdd(&fill[d], 1);
    eSrc[pos] = s;
    eDst[pos] = d;
}

// ---------------------------------------------------------------------------
// Per-edge softmax weights (no max shift: |logit| <~10, exp safe in fp32).
// Pad slots (eSrc=-1) get weight 0 (written here; no memset needed).
// ---------------------------------------------------------------------------
__global__ void k_ew4(const int* __restrict__ eSrc, const int* __restrict__ eDst,
                      const float* __restrict__ als, const float* __restrict__ ald,
                      float* __restrict__ aw) {
    int i = blockIdx.x * blockDim.x + threadIdx.x;
    if (i >= EPAD_MAX) return;
    int s = eSrc[i];
    float4 o = {0.f, 0.f, 0.f, 0.f};
    if (s >= 0) {
        int d = eDst[i];
        float4 av = *(const float4*)(als + (long)s * 4);
        float4 dv = *(const float4*)(ald + (long)d * 4);
        o.x = __expf(lrelu(av.x + dv.x));
        o.y = __expf(lrelu(av.y + dv.y));
        o.z = __expf(lrelu(av.z + dv.z));
        o.w = __expf(lrelu(av.w + dv.w));
    }
    *(float4*)(aw + (long)i * 4) = o;
}

__global__ void k_ew1(const int* __restrict__ eSrc, const int* __restrict__ eDst,
                      const float* __restrict__ als, const float* __restrict__ ald,
                      float* __restrict__ aw) {
    int i = blockIdx.x * blockDim.x + threadIdx.x;
    if (i >= EPAD_MAX) return;
    int s = eSrc[i];
    aw[i] = (s >= 0) ? __expf(lrelu(als[s] + ald[eDst[i]])) : 0.f;
}

// ---------------------------------------------------------------------------
// Cast helpers
// ---------------------------------------------------------------------------
__global__ void k_cast4(const float* __restrict__ in, unsigned short* __restrict__ out,
                        int n4) {
    int i = blockIdx.x * blockDim.x + threadIdx.x;
    if (i >= n4) return;
    float4 v = ((const float4*)in)[i];
    ushort4 o;
    o.x = f2bf(v.x); o.y = f2bf(v.y); o.z = f2bf(v.z); o.w = f2bf(v.w);
    ((ushort4*)out)[i] = o;
}

__global__ void k_wt(const float* __restrict__ W, unsigned short* __restrict__ Wt,
                     int K, int Ncol, int Npad) {
    int i = blockIdx.x * blockDim.x + threadIdx.x;
    if (i >= Npad * K) return;
    int n = i / K, k = i - n * K;
    Wt[n * K + k] = (n < Ncol) ? f2bf(W[(long)k * Ncol + n]) : (unsigned short)0;
}

// ---------------------------------------------------------------------------
// bf16 MFMA GEMM (unchanged)
// ---------------------------------------------------------------------------
#define PITCH 40
template<int BN, int FM, int FN>
__global__ __launch_bounds__(256) void k_mfma(const unsigned short* __restrict__ A,
                                              const unsigned short* __restrict__ Bt,
                                              unsigned short* __restrict__ C,
                                              int M, int K, int Ncol) {
    __shared__ unsigned short As[128 * PITCH];
    __shared__ unsigned short Bs[BN * PITCH];
    const int WCOLS = BN / (FN * 16);
    int tid = threadIdx.x;
    int wave = tid >> 6, lane = tid & 63;
    int quad = lane >> 4, l16 = lane & 15;
    int wr = wave / WCOLS, wc = wave % WCOLS;
    long row0 = (long)blockIdx.x * 128;
    int col0 = blockIdx.y * BN;

    f32x4 acc[FM][FN] = {};

    for (int k0 = 0; k0 < K; k0 += 32) {
        for (int c = tid; c < 512; c += 256) {
            int r = c >> 2, kp = (c & 3) << 3;
            long gr = row0 + r;
            uint4 v = {0u, 0u, 0u, 0u};
            if (gr < M) v = *(const uint4*)(A + gr * K + k0 + kp);
            *(uint4*)(As + r * PITCH + kp) = v;
        }
        for (int c = tid; c < BN * 4; c += 256) {
            int r = c >> 2, kp = (c & 3) << 3;
            uint4 v = *(const uint4*)(Bt + (long)(col0 + r) * K + k0 + kp);
            *(uint4*)(Bs + r * PITCH + kp) = v;
        }
        __syncthreads();
        bf16x8 af[FM], bfr[FN];
        #pragma unroll
        for (int i = 0; i < FM; ++i)
            af[i] = *(const bf16x8*)(As + (wr * FM * 16 + i * 16 + l16) * PITCH + quad * 8);
        #pragma unroll
        for (int j = 0; j < FN; ++j)
            bfr[j] = *(const bf16x8*)(Bs + (wc * FN * 16 + j * 16 + l16) * PITCH + quad * 8);
        #pragma unroll
        for (int i = 0; i < FM; ++i)
            #pragma unroll
            for (int j = 0; j < FN; ++j)
                acc[i][j] = __builtin_amdgcn_mfma_f32_16x16x32_bf16(af[i], bfr[j], acc[i][j], 0, 0, 0);
        __syncthreads();
    }

    #pragma unroll
    for (int i = 0; i < FM; ++i) {
        long rowb = row0 + wr * FM * 16 + i * 16 + quad * 4;
        #pragma unroll
        for (int j = 0; j < FN; ++j) {
            int col = col0 + wc * FN * 16 + j * 16 + l16;
            if (col < Ncol) {
                #pragma unroll
                for (int v = 0; v < 4; ++v) {
                    long r = rowb + v;
                    if (r < M) C[r * Ncol + col] = f2bf(acc[i][j][v]);
                }
            }
        }
    }
}

// ---------------------------------------------------------------------------
// Attention logits
// ---------------------------------------------------------------------------
__global__ __launch_bounds__(256) void k_logits4(const unsigned short* __restrict__ h,
                                                 const float* __restrict__ a_s,
                                                 const float* __restrict__ a_d,
                                                 float* __restrict__ als,
                                                 float* __restrict__ ald) {
    int wave = (blockIdx.x * blockDim.x + threadIdx.x) >> 6;
    int lane = threadIdx.x & 63;
    if (wave >= N_NODES) return;
    ushort4 hu = *(const ushort4*)(h + (long)wave * 256 + lane * 4);
    float hx = bf2f(hu.x), hy = bf2f(hu.y), hz = bf2f(hu.z), hw = bf2f(hu.w);
    int head = lane >> 4;
    int cbase = (lane * 4) & 63;
    float4 sv = *(const float4*)(a_s + head * 64 + cbase);
    float4 dv = *(const float4*)(a_d + head * 64 + cbase);
    float ps = hx * sv.x + hy * sv.y + hz * sv.z + hw * sv.w;
    float pd = hx * dv.x + hy * dv.y + hz * dv.z + hw * dv.w;
    #pragma unroll
    for (int off = 1; off < 16; off <<= 1) {
        ps += __shfl_xor(ps, off);
        pd += __shfl_xor(pd, off);
    }
    if ((lane & 15) == 0) {
        als[wave * 4 + head] = ps;
        ald[wave * 4 + head] = pd;
    }
}

__global__ __launch_bounds__(256) void k_logits1(const unsigned short* __restrict__ h,
                                                 const float* __restrict__ a_s,
                                                 const float* __restrict__ a_d,
                                                 float* __restrict__ als,
                                                 float* __restrict__ ald) {
    int wave = (blockIdx.x * blockDim.x + threadIdx.x) >> 6;
    int lane = threadIdx.x & 63;
    if (wave >= N_NODES) return;
    float hv = (lane < OUT_CH) ? bf2f(h[(long)wave * OUT_CH + lane]) : 0.f;
    float ps = (lane < OUT_CH) ? hv * a_s[lane] : 0.f;
    float pd = (lane < OUT_CH) ? hv * a_d[lane] : 0.f;
    #pragma unroll
    for (int off = 1; off < 64; off <<= 1) {
        ps += __shfl_xor(ps, off);
        pd += __shfl_xor(pd, off);
    }
    if (lane == 0) {
        als[wave] = ps;
        ald[wave] = pd;
    }
}

// ---------------------------------------------------------------------------
// Aggregation (4-head): branch-free x16-unrolled gather-FMA over padded CSR.
// ---------------------------------------------------------------------------
__global__ __launch_bounds__(256) void k_agg4(const unsigned short* __restrict__ h,
                                              const int* __restrict__ start,
                                              const int* __restrict__ deg,
                                              const int* __restrict__ eSrc,
                                              const float* __restrict__ aw,
                                              const float* __restrict__ bias,
                                              unsigned short* __restrict__ out) {
    int node = (blockIdx.x * blockDim.x + threadIdx.x) >> 6;
    int lane = threadIdx.x & 63;
    if (node >= N_NODES) return;
    int st = start[node];
    int dgp = (deg[node] + 15) & ~15;
    int head = lane >> 4;
    const float* awp = aw + (long)st * 4 + head;
    const int* ep = eSrc + st;

    float den = 0.f;
    float4 acc = {0.f, 0.f, 0.f, 0.f};
    for (int j = 0; j < dgp; j += 16) {
        int s[16];
        float w[16];
        #pragma unroll
        for (int u = 0; u < 16; ++u) s[u] = ep[j + u];
        #pragma unroll
        for (int u = 0; u < 16; ++u) w[u] = awp[(j + u) * 4];
        ushort4 hh[16];
        #pragma unroll
        for (int u = 0; u < 16; ++u) {
            int ss = (s[u] < 0) ? 0 : s[u];
            hh[u] = *(const ushort4*)(h + (long)ss * 256 + lane * 4);
        }
        #pragma unroll
        for (int u = 0; u < 16; ++u) {
            den += w[u];
            acc.x += w[u] * bf2f(hh[u].x);
            acc.y += w[u] * bf2f(hh[u].y);
            acc.z += w[u] * bf2f(hh[u].z);
            acc.w += w[u] * bf2f(hh[u].w);
        }
    }
    float inv = 1.f / den;
    int c = lane * 4;
    float4 bv = *(const float4*)(bias + c);
    ushort4 o;
    o.x = f2bf(fmaxf(acc.x * inv + bv.x, 0.f));
    o.y = f2bf(fmaxf(acc.y * inv + bv.y, 0.f));
    o.z = f2bf(fmaxf(acc.z * inv + bv.z, 0.f));
    o.w = f2bf(fmaxf(acc.w * inv + bv.w, 0.f));
    *(ushort4*)(out + (long)node * 256 + c) = o;
}

// ---------------------------------------------------------------------------
// Final layer agg: quad-per-edge. Wave = 4 quads of 16 lanes; each quad owns
// one edge; lanes r<10 hold 4 channels (ushort4) of the 40. 4 edges in
// parallel x 4-deep unroll = 16 outstanding gathers. Fused bias+log_softmax.
// ---------------------------------------------------------------------------
__global__ __launch_bounds__(256) void k_agg1(const unsigned short* __restrict__ h,
                                              const int* __restrict__ start,
                                              const int* __restrict__ deg,
                                              const int* __restrict__ eSrc,
                                              const float* __restrict__ aw,
                                              const float* __restrict__ bias,
                                              float* __restrict__ out) {
    int node = (blockIdx.x * blockDim.x + threadIdx.x) >> 6;
    int lane = threadIdx.x & 63;
    if (node >= N_NODES) return;
    int q = lane >> 4, r = lane & 15;
    bool act = (r < 10);
    int st = start[node];
    int dgp = (deg[node] + 15) & ~15;
    const float* awp = aw + st;
    const int* ep = eSrc + st;

    float den = 0.f;
    float4 acc = {0.f, 0.f, 0.f, 0.f};
    for (int j = 0; j < dgp; j += 16) {
        int base = j + q * 4;
        int s[4];
        float w[4];
        #pragma unroll
        for (int u = 0; u < 4; ++u) s[u] = ep[base + u];
        #pragma unroll
        for (int u = 0; u < 4; ++u) w[u] = awp[base + u];
        ushort4 hh[4];
        #pragma unroll
        for (int u = 0; u < 4; ++u) {
            int ss = (s[u] < 0) ? 0 : s[u];
            ushort4 t = {0, 0, 0, 0};
            if (act) t = *(const ushort4*)(h + (long)ss * OUT_CH + r * 4);
            hh[u] = t;
        }
        #pragma unroll
        for (int u = 0; u < 4; ++u) {
            den += w[u];
            acc.x += w[u] * bf2f(hh[u].x);
            acc.y += w[u] * bf2f(hh[u].y);
            acc.z += w[u] * bf2f(hh[u].z);
            acc.w += w[u] * bf2f(hh[u].w);
        }
    }
    // combine the 4 quads (edge subsets): lanes differing in bits 4,5
    #pragma unroll
    for (int off = 16; off < 64; off <<= 1) {
        acc.x += __shfl_xor(acc.x, off);
        acc.y += __shfl_xor(acc.y, off);
        acc.z += __shfl_xor(acc.z, off);
        acc.w += __shfl_xor(acc.w, off);
        den   += __shfl_xor(den, off);
    }
    float inv = 1.f / den;
    float4 bv = {0.f, 0.f, 0.f, 0.f};
    if (act) bv = *(const float4*)(bias + r * 4);
    float4 v;
    v.x = acc.x * inv + bv.x;
    v.y = acc.y * inv + bv.y;
    v.z = acc.z * inv + bv.z;
    v.w = acc.w * inv + bv.w;
    // log_softmax over 40 channels spread across lanes r=0..9 (x4 each)
    float mx = act ? fmaxf(fmaxf(v.x, v.y), fmaxf(v.z, v.w)) : -INFINITY;
    #pragma unroll
    for (int off = 1; off < 16; off <<= 1) mx = fmaxf(mx, __shfl_xor(mx, off));
    float sum = act ? (__expf(v.x - mx) + __expf(v.y - mx) + __expf(v.z - mx) + __expf(v.w - mx)) : 0.f;
    #pragma unroll
    for (int off = 1; off < 16; off <<= 1) sum += __shfl_xor(sum, off);
    float lse = mx + logf(sum);
    if (q == 0 && act) {
        float4 o;
        o.x = v.x - lse;
        o.y = v.y - lse;
        o.z = v.z - lse;
        o.w = v.w - lse;
        *(float4*)(out + (long)node * OUT_CH + r * 4) = o;
    }
}

// ---------------------------------------------------------------------------
extern "C" void kernel_launch(void* const* d_in, const int* in_sizes, int n_in,
                              void* d_out, int out_size, void* d_ws, size_t ws_size,
                              hipStream_t stream) {
    (void)in_sizes; (void)n_in; (void)out_size; (void)ws_size;
    const float* x   = (const float*)d_in[0];
    const int*   ei  = (const int*)d_in[1];
    const float* W1  = (const float*)d_in[2];
    const float* as1 = (const float*)d_in[3];
    const float* ad1 = (const float*)d_in[4];
    const float* b1  = (const float*)d_in[5];
    const float* W2  = (const float*)d_in[6];
    const float* as2 = (const float*)d_in[7];
    const float* ad2 = (const float*)d_in[8];
    const float* b2  = (const float*)d_in[9];
    const float* W3  = (const float*)d_in[10];
    const float* as3 = (const float*)d_in[11];
    const float* ad3 = (const float*)d_in[12];
    const float* b3  = (const float*)d_in[13];
    float* out = (float*)d_out;

    char* p = (char*)d_ws;
    auto alloc = [&](size_t b) { char* r = p; p += (b + 255) & ~(size_t)255; return r; };
    int*   deg   = (int*)alloc((size_t)N_NODES * 4);
    int*   start = (int*)alloc((size_t)N_NODES * 4);
    int*   fill  = (int*)alloc((size_t)N_NODES * 4);
    int*   bsum  = (int*)alloc(256 * 4);
    int*   eSrc  = (int*)alloc((size_t)EPAD_MAX * 4);
    int*   eDst  = (int*)alloc((size_t)EPAD_MAX * 4);
    float* aw4   = (float*)alloc((size_t)EPAD_MAX * 4 * 4);
    float* aw1   = (float*)alloc((size_t)EPAD_MAX * 4);
    float* als   = (float*)alloc((size_t)N_NODES * 4 * 4);
    float* ald   = (float*)alloc((size_t)N_NODES * 4 * 4);
    unsigned short* xbf  = (unsigned short*)alloc((size_t)N_NODES * IN_CH * 2);
    unsigned short* hAbf = (unsigned short*)alloc((size_t)N_NODES * 256 * 2);
    unsigned short* hBbf = (unsigned short*)alloc((size_t)N_NODES * 256 * 2);
    unsigned short* h3bf = (unsigned short*)alloc((size_t)N_NODES * OUT_CH * 2);
    unsigned short* Wt1  = (unsigned short*)alloc((size_t)256 * IN_CH * 2);
    unsigned short* Wt2  = (unsigned short*)alloc((size_t)256 * 256 * 2);
    unsigned short* Wt3  = (unsigned short*)alloc((size_t)64 * 256 * 2);

    const int NB = (N_NODES + 255) / 256;
    const int EB = (ETOT + 255) / 256;
    const int PB = (EPAD_MAX + 255) / 256;
    const int WB = (N_NODES + 3) / 4;
    const int MB = (N_NODES + 127) / 128;

    // ---- CSR build (padded to multiple of 16 per node) ----
    hipMemsetAsync(deg,  0, (size_t)N_NODES * 4, stream);
    hipMemsetAsync(fill, 0, (size_t)N_NODES * 4, stream);
    hipMemsetAsync(eSrc, 0xFF, (size_t)EPAD_MAX * 4, stream);   // pads -> -1
    k_hist<<<EB, 256, 0, stream>>>(ei, deg);
    k_scan1<<<NB, 256, 0, stream>>>(deg, start, bsum);
    k_scan2<<<1, 256, 0, stream>>>(bsum, NB);
    k_scan3<<<NB, 256, 0, stream>>>(start, bsum);
    k_scatter<<<EB, 256, 0, stream>>>(ei, start, fill, eSrc, eDst);

    // ---- casts ----
    k_cast4<<<(N_NODES * IN_CH / 4 + 255) / 256, 256, 0, stream>>>(x, xbf, N_NODES * IN_CH / 4);
    k_wt<<<(256 * IN_CH + 255) / 256, 256, 0, stream>>>(W1, Wt1, IN_CH, 256, 256);
    k_wt<<<(256 * 256 + 255) / 256, 256, 0, stream>>>(W2, Wt2, 256, 256, 256);
    k_wt<<<(64 * 256 + 255) / 256, 256, 0, stream>>>(W3, Wt3, 256, OUT_CH, 64);

    // ---- layer 1 ----
    k_mfma<128, 4, 4><<<dim3(MB, 2), 256, 0, stream>>>(xbf, Wt1, hAbf, N_NODES, IN_CH, 256);
    k_logits4<<<WB, 256, 0, stream>>>(hAbf, as1, ad1, als, ald);
    k_ew4<<<PB, 256, 0, stream>>>(eSrc, eDst, als, ald, aw4);
    k_agg4<<<WB, 256, 0, stream>>>(hAbf, start, deg, eSrc, aw4, b1, hBbf);

    // ---- layer 2 ----
    k_mfma<128, 4, 4><<<dim3(MB, 2), 256, 0, stream>>>(hBbf, Wt2, hAbf, N_NODES, 256, 256);
    k_logits4<<<WB, 256, 0, stream>>>(hAbf, as2, ad2, als, ald);
    k_ew4<<<PB, 256, 0, stream>>>(eSrc, eDst, als, ald, aw4);
    k_agg4<<<WB, 256, 0, stream>>>(hAbf, start, deg, eSrc, aw4, b2, hBbf);

    // ---- layer 3 ----
    k_mfma<64, 2, 4><<<dim3(MB, 1), 256, 0, stream>>>(hBbf, Wt3, h3bf, N_NODES, 256, OUT_CH);
    k_logits1<<<WB, 256, 0, stream>>>(h3bf, as3, ad3, als, ald);
    k_ew1<<<PB, 256, 0, stream>>>(eSrc, eDst, als, ald, aw1);
    k_agg1<<<WB, 256, 0, stream>>>(h3bf, start, deg, eSrc, aw1, b3, out);
}

// Round 7
// 474.170 us; speedup vs baseline: 1.8890x; 1.0422x over previous
//
#include <hip/hip_runtime.h>
#include <math.h>

#define N_NODES 50000
#define N_EDGES 800000
#define ETOT    (N_EDGES + N_NODES)
#define EPAD_MAX 1200000   // >= sum of per-node degrees rounded up to mult of 8
#define IN_CH   128
#define OUT_CH  40
#define NEG     0.2f

typedef __attribute__((ext_vector_type(8))) short bf16x8;
typedef __attribute__((ext_vector_type(4))) float f32x4;

__device__ inline unsigned short f2bf(float f) {
    unsigned int u = __float_as_uint(f);
    return (unsigned short)((u + 0x7FFFu + ((u >> 16) & 1u)) >> 16);
}
__device__ inline float bf2f(unsigned short u) {
    return __uint_as_float((unsigned int)u << 16);
}
__device__ inline float lrelu(float a) { return (a > 0.f) ? a : NEG * a; }

// ---------------------------------------------------------------------------
// CSR build: histogram of dst, exclusive scan over degrees padded to 8, scatter
// ---------------------------------------------------------------------------
__global__ void k_hist(const int* __restrict__ ei, int* __restrict__ deg) {
    int i = blockIdx.x * blockDim.x + threadIdx.x;
    if (i >= ETOT) return;
    int d = (i < N_EDGES) ? ei[N_EDGES + i] : (i - N_EDGES);
    atomicAdd(&deg[d], 1);
}

__global__ void k_scan1(const int* __restrict__ deg, int* __restrict__ start,
                        int* __restrict__ bsum) {
    __shared__ int sh[256];
    int tid = threadIdx.x;
    int i = blockIdx.x * 256 + tid;
    int v = (i < N_NODES) ? ((deg[i] + 7) & ~7) : 0;   // padded degree
    int x = v;
    sh[tid] = x;
    __syncthreads();
    #pragma unroll
    for (int off = 1; off < 256; off <<= 1) {
        int t = (tid >= off) ? sh[tid - off] : 0;
        __syncthreads();
        x += t;
        sh[tid] = x;
        __syncthreads();
    }
    if (i < N_NODES) start[i] = x - v;
    if (tid == 255) bsum[blockIdx.x] = x;
}

__global__ void k_scan2(int* __restrict__ bsum, int nb) {
    __shared__ int sh[256];
    int tid = threadIdx.x;
    int v = (tid < nb) ? bsum[tid] : 0;
    int x = v;
    sh[tid] = x;
    __syncthreads();
    #pragma unroll
    for (int off = 1; off < 256; off <<= 1) {
        int t = (tid >= off) ? sh[tid - off] : 0;
        __syncthreads();
        x += t;
        sh[tid] = x;
        __syncthreads();
    }
    if (tid < nb) bsum[tid] = x - v;
}

__global__ void k_scan3(int* __restrict__ start, const int* __restrict__ bsum) {
    int i = blockIdx.x * 256 + threadIdx.x;
    if (i < N_NODES) start[i] += bsum[blockIdx.x];
}

__global__ void k_scatter(const int* __restrict__ ei, const int* __restrict__ start,
                          int* __restrict__ fill, int* __restrict__ eSrc) {
    int i = blockIdx.x * blockDim.x + threadIdx.x;
    if (i >= ETOT) return;
    int s, d;
    if (i < N_EDGES) { s = ei[i]; d = ei[N_EDGES + i]; }
    else             { s = i - N_EDGES; d = s; }
    int pos = start[d] + atomicAdd(&fill[d], 1);
    eSrc[pos] = s;
}

// ---------------------------------------------------------------------------
// Cast helpers
// ---------------------------------------------------------------------------
__global__ void k_cast4(const float* __restrict__ in, unsigned short* __restrict__ out,
                        int n4) {
    int i = blockIdx.x * blockDim.x + threadIdx.x;
    if (i >= n4) return;
    float4 v = ((const float4*)in)[i];
    ushort4 o;
    o.x = f2bf(v.x); o.y = f2bf(v.y); o.z = f2bf(v.z); o.w = f2bf(v.w);
    ((ushort4*)out)[i] = o;
}

__global__ void k_wt(const float* __restrict__ W, unsigned short* __restrict__ Wt,
                     int K, int Ncol, int Npad) {
    int i = blockIdx.x * blockDim.x + threadIdx.x;
    if (i >= Npad * K) return;
    int n = i / K, k = i - n * K;
    Wt[n * K + k] = (n < Ncol) ? f2bf(W[(long)k * Ncol + n]) : (unsigned short)0;
}

// ---------------------------------------------------------------------------
// bf16 MFMA GEMM (unchanged)
// ---------------------------------------------------------------------------
#define PITCH 40
template<int BN, int FM, int FN>
__global__ __launch_bounds__(256) void k_mfma(const unsigned short* __restrict__ A,
                                              const unsigned short* __restrict__ Bt,
                                              unsigned short* __restrict__ C,
                                              int M, int K, int Ncol) {
    __shared__ unsigned short As[128 * PITCH];
    __shared__ unsigned short Bs[BN * PITCH];
    const int WCOLS = BN / (FN * 16);
    int tid = threadIdx.x;
    int wave = tid >> 6, lane = tid & 63;
    int quad = lane >> 4, l16 = lane & 15;
    int wr = wave / WCOLS, wc = wave % WCOLS;
    long row0 = (long)blockIdx.x * 128;
    int col0 = blockIdx.y * BN;

    f32x4 acc[FM][FN] = {};

    for (int k0 = 0; k0 < K; k0 += 32) {
        for (int c = tid; c < 512; c += 256) {
            int r = c >> 2, kp = (c & 3) << 3;
            long gr = row0 + r;
            uint4 v = {0u, 0u, 0u, 0u};
            if (gr < M) v = *(const uint4*)(A + gr * K + k0 + kp);
            *(uint4*)(As + r * PITCH + kp) = v;
        }
        for (int c = tid; c < BN * 4; c += 256) {
            int r = c >> 2, kp = (c & 3) << 3;
            uint4 v = *(const uint4*)(Bt + (long)(col0 + r) * K + k0 + kp);
            *(uint4*)(Bs + r * PITCH + kp) = v;
        }
        __syncthreads();
        bf16x8 af[FM], bfr[FN];
        #pragma unroll
        for (int i = 0; i < FM; ++i)
            af[i] = *(const bf16x8*)(As + (wr * FM * 16 + i * 16 + l16) * PITCH + quad * 8);
        #pragma unroll
        for (int j = 0; j < FN; ++j)
            bfr[j] = *(const bf16x8*)(Bs + (wc * FN * 16 + j * 16 + l16) * PITCH + quad * 8);
        #pragma unroll
        for (int i = 0; i < FM; ++i)
            #pragma unroll
            for (int j = 0; j < FN; ++j)
                acc[i][j] = __builtin_amdgcn_mfma_f32_16x16x32_bf16(af[i], bfr[j], acc[i][j], 0, 0, 0);
        __syncthreads();
    }

    #pragma unroll
    for (int i = 0; i < FM; ++i) {
        long rowb = row0 + wr * FM * 16 + i * 16 + quad * 4;
        #pragma unroll
        for (int j = 0; j < FN; ++j) {
            int col = col0 + wc * FN * 16 + j * 16 + l16;
            if (col < Ncol) {
                #pragma unroll
                for (int v = 0; v < 4; ++v) {
                    long r = rowb + v;
                    if (r < M) C[r * Ncol + col] = f2bf(acc[i][j][v]);
                }
            }
        }
    }
}

// ---------------------------------------------------------------------------
// Attention logits
// ---------------------------------------------------------------------------
__global__ __launch_bounds__(256) void k_logits4(const unsigned short* __restrict__ h,
                                                 const float* __restrict__ a_s,
                                                 const float* __restrict__ a_d,
                                                 float* __restrict__ als,
                                                 float* __restrict__ ald) {
    int wave = (blockIdx.x * blockDim.x + threadIdx.x) >> 6;
    int lane = threadIdx.x & 63;
    if (wave >= N_NODES) return;
    ushort4 hu = *(const ushort4*)(h + (long)wave * 256 + lane * 4);
    float hx = bf2f(hu.x), hy = bf2f(hu.y), hz = bf2f(hu.z), hw = bf2f(hu.w);
    int head = lane >> 4;
    int cbase = (lane * 4) & 63;
    float4 sv = *(const float4*)(a_s + head * 64 + cbase);
    float4 dv = *(const float4*)(a_d + head * 64 + cbase);
    float ps = hx * sv.x + hy * sv.y + hz * sv.z + hw * sv.w;
    float pd = hx * dv.x + hy * dv.y + hz * dv.z + hw * dv.w;
    #pragma unroll
    for (int off = 1; off < 16; off <<= 1) {
        ps += __shfl_xor(ps, off);
        pd += __shfl_xor(pd, off);
    }
    if ((lane & 15) == 0) {
        als[wave * 4 + head] = ps;
        ald[wave * 4 + head] = pd;
    }
}

__global__ __launch_bounds__(256) void k_logits1(const unsigned short* __restrict__ h,
                                                 const float* __restrict__ a_s,
                                                 const float* __restrict__ a_d,
                                                 float* __restrict__ als,
                                                 float* __restrict__ ald) {
    int wave = (blockIdx.x * blockDim.x + threadIdx.x) >> 6;
    int lane = threadIdx.x & 63;
    if (wave >= N_NODES) return;
    float hv = (lane < OUT_CH) ? bf2f(h[(long)wave * OUT_CH + lane]) : 0.f;
    float ps = (lane < OUT_CH) ? hv * a_s[lane] : 0.f;
    float pd = (lane < OUT_CH) ? hv * a_d[lane] : 0.f;
    #pragma unroll
    for (int off = 1; off < 64; off <<= 1) {
        ps += __shfl_xor(ps, off);
        pd += __shfl_xor(pd, off);
    }
    if (lane == 0) {
        als[wave] = ps;
        ald[wave] = pd;
    }
}

// ---------------------------------------------------------------------------
// Aggregation (4-head): fused softmax weights, two-ended walk over padded CSR
// (8 slots from the front + 8 from the back per iteration = 16 outstanding
// gathers, pad granularity stays 8). w = exp(lrelu(als[s] + ald[node])).
// No max shift: |logit| <~ 10 so exp is fp32-safe. Pads (s=-1) get w=0.
// ---------------------------------------------------------------------------
__global__ __launch_bounds__(256) void k_agg4(const unsigned short* __restrict__ h,
                                              const int* __restrict__ start,
                                              const int* __restrict__ deg,
                                              const int* __restrict__ eSrc,
                                              const float* __restrict__ als,
                                              const float* __restrict__ ald,
                                              const float* __restrict__ bias,
                                              unsigned short* __restrict__ out) {
    int node = (blockIdx.x * blockDim.x + threadIdx.x) >> 6;
    int lane = threadIdx.x & 63;
    if (node >= N_NODES) return;
    int st = start[node];
    int dgp = (deg[node] + 7) & ~7;
    int head = lane >> 4;
    const int* ep = eSrc + st;
    float aldd = ald[node * 4 + head];

    float den = 0.f;
    float4 acc = {0.f, 0.f, 0.f, 0.f};

    int jA = 0, jB = dgp - 8;
    while (jA < jB) {
        int s[16];
        float w[16];
        #pragma unroll
        for (int u = 0; u < 8; ++u) { s[u] = ep[jA + u]; s[8 + u] = ep[jB + u]; }
        #pragma unroll
        for (int u = 0; u < 16; ++u) {
            int raw = s[u];
            int ss = (raw < 0) ? 0 : raw;
            float a = lrelu(als[(long)ss * 4 + head] + aldd);
            w[u] = (raw < 0) ? 0.f : __expf(a);
            s[u] = ss;
        }
        ushort4 hh[16];
        #pragma unroll
        for (int u = 0; u < 16; ++u)
            hh[u] = *(const ushort4*)(h + (long)s[u] * 256 + lane * 4);
        #pragma unroll
        for (int u = 0; u < 16; ++u) {
            den += w[u];
            acc.x += w[u] * bf2f(hh[u].x);
            acc.y += w[u] * bf2f(hh[u].y);
            acc.z += w[u] * bf2f(hh[u].z);
            acc.w += w[u] * bf2f(hh[u].w);
        }
        jA += 8; jB -= 8;
    }
    if (jA == jB) {
        int s[8];
        float w[8];
        #pragma unroll
        for (int u = 0; u < 8; ++u) s[u] = ep[jA + u];
        #pragma unroll
        for (int u = 0; u < 8; ++u) {
            int raw = s[u];
            int ss = (raw < 0) ? 0 : raw;
            float a = lrelu(als[(long)ss * 4 + head] + aldd);
            w[u] = (raw < 0) ? 0.f : __expf(a);
            s[u] = ss;
        }
        ushort4 hh[8];
        #pragma unroll
        for (int u = 0; u < 8; ++u)
            hh[u] = *(const ushort4*)(h + (long)s[u] * 256 + lane * 4);
        #pragma unroll
        for (int u = 0; u < 8; ++u) {
            den += w[u];
            acc.x += w[u] * bf2f(hh[u].x);
            acc.y += w[u] * bf2f(hh[u].y);
            acc.z += w[u] * bf2f(hh[u].z);
            acc.w += w[u] * bf2f(hh[u].w);
        }
    }

    float inv = 1.f / den;
    int c = lane * 4;
    float4 bv = *(const float4*)(bias + c);
    ushort4 o;
    o.x = f2bf(fmaxf(acc.x * inv + bv.x, 0.f));
    o.y = f2bf(fmaxf(acc.y * inv + bv.y, 0.f));
    o.z = f2bf(fmaxf(acc.z * inv + bv.z, 0.f));
    o.w = f2bf(fmaxf(acc.w * inv + bv.w, 0.f));
    *(ushort4*)(out + (long)node * 256 + c) = o;
}

// ---------------------------------------------------------------------------
// Final layer agg: quad-per-edge, two-ended walk (4 front + 4 back slots per
// iteration; each quad holds 2 edges -> 8 outstanding gathers). Fused weight
// computation + bias + log_softmax. Lanes r<10 hold 4 channels of the 40.
// ---------------------------------------------------------------------------
__global__ __launch_bounds__(256) void k_agg1(const unsigned short* __restrict__ h,
                                              const int* __restrict__ start,
                                              const int* __restrict__ deg,
                                              const int* __restrict__ eSrc,
                                              const float* __restrict__ als,
                                              const float* __restrict__ ald,
                                              const float* __restrict__ bias,
                                              float* __restrict__ out) {
    int node = (blockIdx.x * blockDim.x + threadIdx.x) >> 6;
    int lane = threadIdx.x & 63;
    if (node >= N_NODES) return;
    int q = lane >> 4, r = lane & 15;
    bool act = (r < 10);
    int st = start[node];
    int dgp = (deg[node] + 7) & ~7;
    const int* ep = eSrc + st;
    float aldd = ald[node];

    float den = 0.f;
    float4 acc = {0.f, 0.f, 0.f, 0.f};

    int jA = 0, jB = dgp - 4;
    while (jA < jB) {
        int r0 = ep[jA + q], r1 = ep[jB + q];
        int s0 = (r0 < 0) ? 0 : r0;
        int s1 = (r1 < 0) ? 0 : r1;
        float w0 = (r0 < 0) ? 0.f : __expf(lrelu(als[s0] + aldd));
        float w1 = (r1 < 0) ? 0.f : __expf(lrelu(als[s1] + aldd));
        ushort4 h0 = {0, 0, 0, 0}, h1 = {0, 0, 0, 0};
        if (act) {
            h0 = *(const ushort4*)(h + (long)s0 * OUT_CH + r * 4);
            h1 = *(const ushort4*)(h + (long)s1 * OUT_CH + r * 4);
        }
        den += w0 + w1;
        acc.x += w0 * bf2f(h0.x) + w1 * bf2f(h1.x);
        acc.y += w0 * bf2f(h0.y) + w1 * bf2f(h1.y);
        acc.z += w0 * bf2f(h0.z) + w1 * bf2f(h1.z);
        acc.w += w0 * bf2f(h0.w) + w1 * bf2f(h1.w);
        jA += 4; jB -= 4;
    }
    if (jA == jB) {   // unreachable for dgp mult of 8, kept for safety
        int r0 = ep[jA + q];
        int s0 = (r0 < 0) ? 0 : r0;
        float w0 = (r0 < 0) ? 0.f : __expf(lrelu(als[s0] + aldd));
        ushort4 h0 = {0, 0, 0, 0};
        if (act) h0 = *(const ushort4*)(h + (long)s0 * OUT_CH + r * 4);
        den += w0;
        acc.x += w0 * bf2f(h0.x);
        acc.y += w0 * bf2f(h0.y);
        acc.z += w0 * bf2f(h0.z);
        acc.w += w0 * bf2f(h0.w);
    }

    // combine the 4 quads (edge subsets)
    #pragma unroll
    for (int off = 16; off < 64; off <<= 1) {
        acc.x += __shfl_xor(acc.x, off);
        acc.y += __shfl_xor(acc.y, off);
        acc.z += __shfl_xor(acc.z, off);
        acc.w += __shfl_xor(acc.w, off);
        den   += __shfl_xor(den, off);
    }
    float inv = 1.f / den;
    float4 bv = {0.f, 0.f, 0.f, 0.f};
    if (act) bv = *(const float4*)(bias + r * 4);
    float4 v;
    v.x = acc.x * inv + bv.x;
    v.y = acc.y * inv + bv.y;
    v.z = acc.z * inv + bv.z;
    v.w = acc.w * inv + bv.w;
    // log_softmax over 40 channels spread across lanes r=0..9 (x4 each)
    float mx = act ? fmaxf(fmaxf(v.x, v.y), fmaxf(v.z, v.w)) : -INFINITY;
    #pragma unroll
    for (int off = 1; off < 16; off <<= 1) mx = fmaxf(mx, __shfl_xor(mx, off));
    float sum = act ? (__expf(v.x - mx) + __expf(v.y - mx) + __expf(v.z - mx) + __expf(v.w - mx)) : 0.f;
    #pragma unroll
    for (int off = 1; off < 16; off <<= 1) sum += __shfl_xor(sum, off);
    float lse = mx + logf(sum);
    if (q == 0 && act) {
        float4 o;
        o.x = v.x - lse;
        o.y = v.y - lse;
        o.z = v.z - lse;
        o.w = v.w - lse;
        *(float4*)(out + (long)node * OUT_CH + r * 4) = o;
    }
}

// ---------------------------------------------------------------------------
extern "C" void kernel_launch(void* const* d_in, const int* in_sizes, int n_in,
                              void* d_out, int out_size, void* d_ws, size_t ws_size,
                              hipStream_t stream) {
    (void)in_sizes; (void)n_in; (void)out_size; (void)ws_size;
    const float* x   = (const float*)d_in[0];
    const int*   ei  = (const int*)d_in[1];
    const float* W1  = (const float*)d_in[2];
    const float* as1 = (const float*)d_in[3];
    const float* ad1 = (const float*)d_in[4];
    const float* b1  = (const float*)d_in[5];
    const float* W2  = (const float*)d_in[6];
    const float* as2 = (const float*)d_in[7];
    const float* ad2 = (const float*)d_in[8];
    const float* b2  = (const float*)d_in[9];
    const float* W3  = (const float*)d_in[10];
    const float* as3 = (const float*)d_in[11];
    const float* ad3 = (const float*)d_in[12];
    const float* b3  = (const float*)d_in[13];
    float* out = (float*)d_out;

    char* p = (char*)d_ws;
    auto alloc = [&](size_t b) { char* r = p; p += (b + 255) & ~(size_t)255; return r; };
    int*   deg   = (int*)alloc((size_t)N_NODES * 4);
    int*   start = (int*)alloc((size_t)N_NODES * 4);
    int*   fill  = (int*)alloc((size_t)N_NODES * 4);
    int*   bsum  = (int*)alloc(256 * 4);
    int*   eSrc  = (int*)alloc((size_t)EPAD_MAX * 4);
    float* als   = (float*)alloc((size_t)N_NODES * 4 * 4);
    float* ald   = (float*)alloc((size_t)N_NODES * 4 * 4);
    unsigned short* xbf  = (unsigned short*)alloc((size_t)N_NODES * IN_CH * 2);
    unsigned short* hAbf = (unsigned short*)alloc((size_t)N_NODES * 256 * 2);
    unsigned short* hBbf = (unsigned short*)alloc((size_t)N_NODES * 256 * 2);
    unsigned short* h3bf = (unsigned short*)alloc((size_t)N_NODES * OUT_CH * 2);
    unsigned short* Wt1  = (unsigned short*)alloc((size_t)256 * IN_CH * 2);
    unsigned short* Wt2  = (unsigned short*)alloc((size_t)256 * 256 * 2);
    unsigned short* Wt3  = (unsigned short*)alloc((size_t)64 * 256 * 2);

    const int NB = (N_NODES + 255) / 256;
    const int EB = (ETOT + 255) / 256;
    const int WB = (N_NODES + 3) / 4;
    const int MB = (N_NODES + 127) / 128;

    // ---- CSR build (padded to multiple of 8 per node) ----
    hipMemsetAsync(deg,  0, (size_t)N_NODES * 4, stream);
    hipMemsetAsync(fill, 0, (size_t)N_NODES * 4, stream);
    hipMemsetAsync(eSrc, 0xFF, (size_t)EPAD_MAX * 4, stream);   // pads -> -1
    k_hist<<<EB, 256, 0, stream>>>(ei, deg);
    k_scan1<<<NB, 256, 0, stream>>>(deg, start, bsum);
    k_scan2<<<1, 256, 0, stream>>>(bsum, NB);
    k_scan3<<<NB, 256, 0, stream>>>(start, bsum);
    k_scatter<<<EB, 256, 0, stream>>>(ei, start, fill, eSrc);

    // ---- casts ----
    k_cast4<<<(N_NODES * IN_CH / 4 + 255) / 256, 256, 0, stream>>>(x, xbf, N_NODES * IN_CH / 4);
    k_wt<<<(256 * IN_CH + 255) / 256, 256, 0, stream>>>(W1, Wt1, IN_CH, 256, 256);
    k_wt<<<(256 * 256 + 255) / 256, 256, 0, stream>>>(W2, Wt2, 256, 256, 256);
    k_wt<<<(64 * 256 + 255) / 256, 256, 0, stream>>>(W3, Wt3, 256, OUT_CH, 64);

    // ---- layer 1 ----
    k_mfma<128, 4, 4><<<dim3(MB, 2), 256, 0, stream>>>(xbf, Wt1, hAbf, N_NODES, IN_CH, 256);
    k_logits4<<<WB, 256, 0, stream>>>(hAbf, as1, ad1, als, ald);
    k_agg4<<<WB, 256, 0, stream>>>(hAbf, start, deg, eSrc, als, ald, b1, hBbf);

    // ---- layer 2 ----
    k_mfma<128, 4, 4><<<dim3(MB, 2), 256, 0, stream>>>(hBbf, Wt2, hAbf, N_NODES, 256, 256);
    k_logits4<<<WB, 256, 0, stream>>>(hAbf, as2, ad2, als, ald);
    k_agg4<<<WB, 256, 0, stream>>>(hAbf, start, deg, eSrc, als, ald, b2, hBbf);

    // ---- layer 3 ----
    k_mfma<64, 2, 4><<<dim3(MB, 1), 256, 0, stream>>>(hBbf, Wt3, h3bf, N_NODES, 256, OUT_CH);
    k_logits1<<<WB, 256, 0, stream>>>(h3bf, as3, ad3, als, ald);
    k_agg1<<<WB, 256, 0, stream>>>(h3bf, start, deg, eSrc, als, ald, b3, out);
}

// Round 8
// 448.110 us; speedup vs baseline: 1.9988x; 1.0582x over previous
//
#include <hip/hip_runtime.h>
#include <math.h>

#define N_NODES 50000
#define N_EDGES 800000
#define ETOT    (N_EDGES + N_NODES)
#define EPAD_MAX 1200000   // >= sum of per-node degrees rounded up to mult of 8
#define IN_CH   128
#define OUT_CH  40
#define NEG     0.2f
#define CAP     128        // max cached slots per node (Poisson(17) max ~45)

typedef __attribute__((ext_vector_type(8))) short bf16x8;
typedef __attribute__((ext_vector_type(4))) float f32x4;

__device__ inline unsigned short f2bf(float f) {
    unsigned int u = __float_as_uint(f);
    return (unsigned short)((u + 0x7FFFu + ((u >> 16) & 1u)) >> 16);
}
__device__ inline float bf2f(unsigned short u) {
    return __uint_as_float((unsigned int)u << 16);
}
__device__ inline float lrelu(float a) { return (a > 0.f) ? a : NEG * a; }

// ---------------------------------------------------------------------------
// CSR build: histogram of dst, exclusive scan over degrees padded to 8, scatter
// ---------------------------------------------------------------------------
__global__ void k_hist(const int* __restrict__ ei, int* __restrict__ deg) {
    int i = blockIdx.x * blockDim.x + threadIdx.x;
    if (i >= ETOT) return;
    int d = (i < N_EDGES) ? ei[N_EDGES + i] : (i - N_EDGES);
    atomicAdd(&deg[d], 1);
}

__global__ void k_scan1(const int* __restrict__ deg, int* __restrict__ start,
                        int* __restrict__ bsum) {
    __shared__ int sh[256];
    int tid = threadIdx.x;
    int i = blockIdx.x * 256 + tid;
    int v = (i < N_NODES) ? ((deg[i] + 7) & ~7) : 0;   // padded degree
    int x = v;
    sh[tid] = x;
    __syncthreads();
    #pragma unroll
    for (int off = 1; off < 256; off <<= 1) {
        int t = (tid >= off) ? sh[tid - off] : 0;
        __syncthreads();
        x += t;
        sh[tid] = x;
        __syncthreads();
    }
    if (i < N_NODES) start[i] = x - v;
    if (tid == 255) bsum[blockIdx.x] = x;
}

__global__ void k_scan2(int* __restrict__ bsum, int nb) {
    __shared__ int sh[256];
    int tid = threadIdx.x;
    int v = (tid < nb) ? bsum[tid] : 0;
    int x = v;
    sh[tid] = x;
    __syncthreads();
    #pragma unroll
    for (int off = 1; off < 256; off <<= 1) {
        int t = (tid >= off) ? sh[tid - off] : 0;
        __syncthreads();
        x += t;
        sh[tid] = x;
        __syncthreads();
    }
    if (tid < nb) bsum[tid] = x - v;
}

__global__ void k_scan3(int* __restrict__ start, const int* __restrict__ bsum) {
    int i = blockIdx.x * 256 + threadIdx.x;
    if (i < N_NODES) start[i] += bsum[blockIdx.x];
}

__global__ void k_scatter(const int* __restrict__ ei, const int* __restrict__ start,
                          int* __restrict__ fill, int* __restrict__ eSrc) {
    int i = blockIdx.x * blockDim.x + threadIdx.x;
    if (i >= ETOT) return;
    int s, d;
    if (i < N_EDGES) { s = ei[i]; d = ei[N_EDGES + i]; }
    else             { s = i - N_EDGES; d = s; }
    int pos = start[d] + atomicAdd(&fill[d], 1);
    eSrc[pos] = s;
}

// ---------------------------------------------------------------------------
// Weight transpose cast: W[K][N] fp32 -> Wt[Npad][K] bf16
// ---------------------------------------------------------------------------
__global__ void k_wt(const float* __restrict__ W, unsigned short* __restrict__ Wt,
                     int K, int Ncol, int Npad) {
    int i = blockIdx.x * blockDim.x + threadIdx.x;
    if (i >= Npad * K) return;
    int n = i / K, k = i - n * K;
    Wt[n * K + k] = (n < Ncol) ? f2bf(W[(long)k * Ncol + n]) : (unsigned short)0;
}

// ---------------------------------------------------------------------------
// bf16 MFMA GEMM. CVT=true: A is fp32, converted to bf16 during LDS staging.
// ---------------------------------------------------------------------------
#define PITCH 40
template<int BN, int FM, int FN, bool CVT>
__global__ __launch_bounds__(256) void k_mfma(const void* __restrict__ Araw,
                                              const unsigned short* __restrict__ Bt,
                                              unsigned short* __restrict__ C,
                                              int M, int K, int Ncol) {
    __shared__ unsigned short As[128 * PITCH];
    __shared__ unsigned short Bs[BN * PITCH];
    const int WCOLS = BN / (FN * 16);
    int tid = threadIdx.x;
    int wave = tid >> 6, lane = tid & 63;
    int quad = lane >> 4, l16 = lane & 15;
    int wr = wave / WCOLS, wc = wave % WCOLS;
    long row0 = (long)blockIdx.x * 128;
    int col0 = blockIdx.y * BN;

    f32x4 acc[FM][FN] = {};

    for (int k0 = 0; k0 < K; k0 += 32) {
        for (int c = tid; c < 512; c += 256) {
            int r = c >> 2, kp = (c & 3) << 3;
            long gr = row0 + r;
            if (CVT) {
                const float* A32 = (const float*)Araw;
                ushort4 lo = {0,0,0,0}, hi = {0,0,0,0};
                if (gr < M) {
                    float4 v0 = *(const float4*)(A32 + gr * K + k0 + kp);
                    float4 v1 = *(const float4*)(A32 + gr * K + k0 + kp + 4);
                    lo.x = f2bf(v0.x); lo.y = f2bf(v0.y); lo.z = f2bf(v0.z); lo.w = f2bf(v0.w);
                    hi.x = f2bf(v1.x); hi.y = f2bf(v1.y); hi.z = f2bf(v1.z); hi.w = f2bf(v1.w);
                }
                *(ushort4*)(As + r * PITCH + kp) = lo;
                *(ushort4*)(As + r * PITCH + kp + 4) = hi;
            } else {
                const unsigned short* A16 = (const unsigned short*)Araw;
                uint4 v = {0u, 0u, 0u, 0u};
                if (gr < M) v = *(const uint4*)(A16 + gr * K + k0 + kp);
                *(uint4*)(As + r * PITCH + kp) = v;
            }
        }
        for (int c = tid; c < BN * 4; c += 256) {
            int r = c >> 2, kp = (c & 3) << 3;
            uint4 v = *(const uint4*)(Bt + (long)(col0 + r) * K + k0 + kp);
            *(uint4*)(Bs + r * PITCH + kp) = v;
        }
        __syncthreads();
        bf16x8 af[FM], bfr[FN];
        #pragma unroll
        for (int i = 0; i < FM; ++i)
            af[i] = *(const bf16x8*)(As + (wr * FM * 16 + i * 16 + l16) * PITCH + quad * 8);
        #pragma unroll
        for (int j = 0; j < FN; ++j)
            bfr[j] = *(const bf16x8*)(Bs + (wc * FN * 16 + j * 16 + l16) * PITCH + quad * 8);
        #pragma unroll
        for (int i = 0; i < FM; ++i)
            #pragma unroll
            for (int j = 0; j < FN; ++j)
                acc[i][j] = __builtin_amdgcn_mfma_f32_16x16x32_bf16(af[i], bfr[j], acc[i][j], 0, 0, 0);
        __syncthreads();
    }

    #pragma unroll
    for (int i = 0; i < FM; ++i) {
        long rowb = row0 + wr * FM * 16 + i * 16 + quad * 4;
        #pragma unroll
        for (int j = 0; j < FN; ++j) {
            int col = col0 + wc * FN * 16 + j * 16 + l16;
            if (col < Ncol) {
                #pragma unroll
                for (int v = 0; v < 4; ++v) {
                    long r = rowb + v;
                    if (r < M) C[r * Ncol + col] = f2bf(acc[i][j][v]);
                }
            }
        }
    }
}

// ---------------------------------------------------------------------------
// Attention logits
// ---------------------------------------------------------------------------
__global__ __launch_bounds__(256) void k_logits4(const unsigned short* __restrict__ h,
                                                 const float* __restrict__ a_s,
                                                 const float* __restrict__ a_d,
                                                 float* __restrict__ als,
                                                 float* __restrict__ ald) {
    int wave = (blockIdx.x * blockDim.x + threadIdx.x) >> 6;
    int lane = threadIdx.x & 63;
    if (wave >= N_NODES) return;
    ushort4 hu = *(const ushort4*)(h + (long)wave * 256 + lane * 4);
    float hx = bf2f(hu.x), hy = bf2f(hu.y), hz = bf2f(hu.z), hw = bf2f(hu.w);
    int head = lane >> 4;
    int cbase = (lane * 4) & 63;
    float4 sv = *(const float4*)(a_s + head * 64 + cbase);
    float4 dv = *(const float4*)(a_d + head * 64 + cbase);
    float ps = hx * sv.x + hy * sv.y + hz * sv.z + hw * sv.w;
    float pd = hx * dv.x + hy * dv.y + hz * dv.z + hw * dv.w;
    #pragma unroll
    for (int off = 1; off < 16; off <<= 1) {
        ps += __shfl_xor(ps, off);
        pd += __shfl_xor(pd, off);
    }
    if ((lane & 15) == 0) {
        als[wave * 4 + head] = ps;
        ald[wave * 4 + head] = pd;
    }
}

__global__ __launch_bounds__(256) void k_logits1(const unsigned short* __restrict__ h,
                                                 const float* __restrict__ a_s,
                                                 const float* __restrict__ a_d,
                                                 float* __restrict__ als,
                                                 float* __restrict__ ald) {
    int wave = (blockIdx.x * blockDim.x + threadIdx.x) >> 6;
    int lane = threadIdx.x & 63;
    if (wave >= N_NODES) return;
    float hv = (lane < OUT_CH) ? bf2f(h[(long)wave * OUT_CH + lane]) : 0.f;
    float ps = (lane < OUT_CH) ? hv * a_s[lane] : 0.f;
    float pd = (lane < OUT_CH) ? hv * a_d[lane] : 0.f;
    #pragma unroll
    for (int off = 1; off < 64; off <<= 1) {
        ps += __shfl_xor(ps, off);
        pd += __shfl_xor(pd, off);
    }
    if (lane == 0) {
        als[wave] = ps;
        ald[wave] = pd;
    }
}

// ---------------------------------------------------------------------------
// Aggregation (4-head). Phase 1: cooperative weight computation into LDS —
// lane (l16, head) computes w for slot c+l16 / head lane>>4, so ONE exp issue
// covers 16 slots x 4 heads. Phase 2: two-ended x16 gather-FMA reading s,w
// from wave-private LDS (broadcast, conflict-free). Overflow >CAP: inline.
// ---------------------------------------------------------------------------
__global__ __launch_bounds__(256) void k_agg4(const unsigned short* __restrict__ h,
                                              const int* __restrict__ start,
                                              const int* __restrict__ deg,
                                              const int* __restrict__ eSrc,
                                              const float* __restrict__ als,
                                              const float* __restrict__ ald,
                                              const float* __restrict__ bias,
                                              unsigned short* __restrict__ out) {
    __shared__ float wbuf[4][CAP * 4];
    __shared__ int   sbuf[4][CAP];
    int wid = threadIdx.x >> 6;
    int node = (blockIdx.x * blockDim.x + threadIdx.x) >> 6;
    int lane = threadIdx.x & 63;
    if (node >= N_NODES) return;
    int st = start[node];
    int dgp = (deg[node] + 7) & ~7;
    int head = lane >> 4, l16 = lane & 15;
    const int* ep = eSrc + st;
    float aldd = ald[node * 4 + head];

    // ---- phase 1: weights into LDS ----
    int ncap = (dgp < CAP) ? dgp : CAP;
    for (int c = 0; c < ncap; c += 16) {
        int slot = c + l16;
        bool ok = (slot < ncap);
        int raw = ok ? ep[slot] : -1;
        int ss = (raw < 0) ? 0 : raw;
        float a = als[(long)ss * 4 + head] + aldd;
        float w = (raw < 0) ? 0.f : __expf(lrelu(a));
        if (ok) {
            wbuf[wid][slot * 4 + head] = w;
            if (head == 0) sbuf[wid][slot] = ss;
        }
    }

    // ---- phase 2: two-ended x16 gather-FMA ----
    float den = 0.f;
    float4 acc = {0.f, 0.f, 0.f, 0.f};
    int jA = 0, jB = ncap - 8;
    while (jA < jB) {
        int s[16];
        float w[16];
        #pragma unroll
        for (int u = 0; u < 8; ++u) {
            s[u]     = sbuf[wid][jA + u];
            s[8 + u] = sbuf[wid][jB + u];
            w[u]     = wbuf[wid][(jA + u) * 4 + head];
            w[8 + u] = wbuf[wid][(jB + u) * 4 + head];
        }
        ushort4 hh[16];
        #pragma unroll
        for (int u = 0; u < 16; ++u)
            hh[u] = *(const ushort4*)(h + (long)s[u] * 256 + lane * 4);
        #pragma unroll
        for (int u = 0; u < 16; ++u) {
            den += w[u];
            acc.x += w[u] * bf2f(hh[u].x);
            acc.y += w[u] * bf2f(hh[u].y);
            acc.z += w[u] * bf2f(hh[u].z);
            acc.w += w[u] * bf2f(hh[u].w);
        }
        jA += 8; jB -= 8;
    }
    if (jA == jB) {
        int s[8];
        float w[8];
        #pragma unroll
        for (int u = 0; u < 8; ++u) {
            s[u] = sbuf[wid][jA + u];
            w[u] = wbuf[wid][(jA + u) * 4 + head];
        }
        ushort4 hh[8];
        #pragma unroll
        for (int u = 0; u < 8; ++u)
            hh[u] = *(const ushort4*)(h + (long)s[u] * 256 + lane * 4);
        #pragma unroll
        for (int u = 0; u < 8; ++u) {
            den += w[u];
            acc.x += w[u] * bf2f(hh[u].x);
            acc.y += w[u] * bf2f(hh[u].y);
            acc.z += w[u] * bf2f(hh[u].z);
            acc.w += w[u] * bf2f(hh[u].w);
        }
    }
    // ---- overflow beyond CAP (practically never taken) ----
    for (int j = CAP; j < dgp; j += 8) {
        #pragma unroll
        for (int u = 0; u < 8; ++u) {
            int raw = ep[j + u];
            int ss = (raw < 0) ? 0 : raw;
            float a = lrelu(als[(long)ss * 4 + head] + aldd);
            float w = (raw < 0) ? 0.f : __expf(a);
            ushort4 hv = *(const ushort4*)(h + (long)ss * 256 + lane * 4);
            den += w;
            acc.x += w * bf2f(hv.x);
            acc.y += w * bf2f(hv.y);
            acc.z += w * bf2f(hv.z);
            acc.w += w * bf2f(hv.w);
        }
    }

    float inv = 1.f / den;
    int c = lane * 4;
    float4 bv = *(const float4*)(bias + c);
    ushort4 o;
    o.x = f2bf(fmaxf(acc.x * inv + bv.x, 0.f));
    o.y = f2bf(fmaxf(acc.y * inv + bv.y, 0.f));
    o.z = f2bf(fmaxf(acc.z * inv + bv.z, 0.f));
    o.w = f2bf(fmaxf(acc.w * inv + bv.w, 0.f));
    *(ushort4*)(out + (long)node * 256 + c) = o;
}

// ---------------------------------------------------------------------------
// Final layer agg: quad-per-edge, two-ended walk, fused weights + bias +
// log_softmax (unchanged from R7).
// ---------------------------------------------------------------------------
__global__ __launch_bounds__(256) void k_agg1(const unsigned short* __restrict__ h,
                                              const int* __restrict__ start,
                                              const int* __restrict__ deg,
                                              const int* __restrict__ eSrc,
                                              const float* __restrict__ als,
                                              const float* __restrict__ ald,
                                              const float* __restrict__ bias,
                                              float* __restrict__ out) {
    int node = (blockIdx.x * blockDim.x + threadIdx.x) >> 6;
    int lane = threadIdx.x & 63;
    if (node >= N_NODES) return;
    int q = lane >> 4, r = lane & 15;
    bool act = (r < 10);
    int st = start[node];
    int dgp = (deg[node] + 7) & ~7;
    const int* ep = eSrc + st;
    float aldd = ald[node];

    float den = 0.f;
    float4 acc = {0.f, 0.f, 0.f, 0.f};

    int jA = 0, jB = dgp - 4;
    while (jA < jB) {
        int r0 = ep[jA + q], r1 = ep[jB + q];
        int s0 = (r0 < 0) ? 0 : r0;
        int s1 = (r1 < 0) ? 0 : r1;
        float w0 = (r0 < 0) ? 0.f : __expf(lrelu(als[s0] + aldd));
        float w1 = (r1 < 0) ? 0.f : __expf(lrelu(als[s1] + aldd));
        ushort4 h0 = {0, 0, 0, 0}, h1 = {0, 0, 0, 0};
        if (act) {
            h0 = *(const ushort4*)(h + (long)s0 * OUT_CH + r * 4);
            h1 = *(const ushort4*)(h + (long)s1 * OUT_CH + r * 4);
        }
        den += w0 + w1;
        acc.x += w0 * bf2f(h0.x) + w1 * bf2f(h1.x);
        acc.y += w0 * bf2f(h0.y) + w1 * bf2f(h1.y);
        acc.z += w0 * bf2f(h0.z) + w1 * bf2f(h1.z);
        acc.w += w0 * bf2f(h0.w) + w1 * bf2f(h1.w);
        jA += 4; jB -= 4;
    }
    if (jA == jB) {
        int r0 = ep[jA + q];
        int s0 = (r0 < 0) ? 0 : r0;
        float w0 = (r0 < 0) ? 0.f : __expf(lrelu(als[s0] + aldd));
        ushort4 h0 = {0, 0, 0, 0};
        if (act) h0 = *(const ushort4*)(h + (long)s0 * OUT_CH + r * 4);
        den += w0;
        acc.x += w0 * bf2f(h0.x);
        acc.y += w0 * bf2f(h0.y);
        acc.z += w0 * bf2f(h0.z);
        acc.w += w0 * bf2f(h0.w);
    }

    #pragma unroll
    for (int off = 16; off < 64; off <<= 1) {
        acc.x += __shfl_xor(acc.x, off);
        acc.y += __shfl_xor(acc.y, off);
        acc.z += __shfl_xor(acc.z, off);
        acc.w += __shfl_xor(acc.w, off);
        den   += __shfl_xor(den, off);
    }
    float inv = 1.f / den;
    float4 bv = {0.f, 0.f, 0.f, 0.f};
    if (act) bv = *(const float4*)(bias + r * 4);
    float4 v;
    v.x = acc.x * inv + bv.x;
    v.y = acc.y * inv + bv.y;
    v.z = acc.z * inv + bv.z;
    v.w = acc.w * inv + bv.w;
    float mx = act ? fmaxf(fmaxf(v.x, v.y), fmaxf(v.z, v.w)) : -INFINITY;
    #pragma unroll
    for (int off = 1; off < 16; off <<= 1) mx = fmaxf(mx, __shfl_xor(mx, off));
    float sum = act ? (__expf(v.x - mx) + __expf(v.y - mx) + __expf(v.z - mx) + __expf(v.w - mx)) : 0.f;
    #pragma unroll
    for (int off = 1; off < 16; off <<= 1) sum += __shfl_xor(sum, off);
    float lse = mx + logf(sum);
    if (q == 0 && act) {
        float4 o;
        o.x = v.x - lse;
        o.y = v.y - lse;
        o.z = v.z - lse;
        o.w = v.w - lse;
        *(float4*)(out + (long)node * OUT_CH + r * 4) = o;
    }
}

// ---------------------------------------------------------------------------
extern "C" void kernel_launch(void* const* d_in, const int* in_sizes, int n_in,
                              void* d_out, int out_size, void* d_ws, size_t ws_size,
                              hipStream_t stream) {
    (void)in_sizes; (void)n_in; (void)out_size; (void)ws_size;
    const float* x   = (const float*)d_in[0];
    const int*   ei  = (const int*)d_in[1];
    const float* W1  = (const float*)d_in[2];
    const float* as1 = (const float*)d_in[3];
    const float* ad1 = (const float*)d_in[4];
    const float* b1  = (const float*)d_in[5];
    const float* W2  = (const float*)d_in[6];
    const float* as2 = (const float*)d_in[7];
    const float* ad2 = (const float*)d_in[8];
    const float* b2  = (const float*)d_in[9];
    const float* W3  = (const float*)d_in[10];
    const float* as3 = (const float*)d_in[11];
    const float* ad3 = (const float*)d_in[12];
    const float* b3  = (const float*)d_in[13];
    float* out = (float*)d_out;

    char* p = (char*)d_ws;
    auto alloc = [&](size_t b) { char* r = p; p += (b + 255) & ~(size_t)255; return r; };
    int*   deg   = (int*)alloc((size_t)N_NODES * 4);
    int*   start = (int*)alloc((size_t)N_NODES * 4);
    int*   fill  = (int*)alloc((size_t)N_NODES * 4);
    int*   bsum  = (int*)alloc(256 * 4);
    int*   eSrc  = (int*)alloc((size_t)EPAD_MAX * 4);
    float* als   = (float*)alloc((size_t)N_NODES * 4 * 4);
    float* ald   = (float*)alloc((size_t)N_NODES * 4 * 4);
    unsigned short* hAbf = (unsigned short*)alloc((size_t)N_NODES * 256 * 2);
    unsigned short* hBbf = (unsigned short*)alloc((size_t)N_NODES * 256 * 2);
    unsigned short* h3bf = (unsigned short*)alloc((size_t)N_NODES * OUT_CH * 2);
    unsigned short* Wt1  = (unsigned short*)alloc((size_t)256 * IN_CH * 2);
    unsigned short* Wt2  = (unsigned short*)alloc((size_t)256 * 256 * 2);
    unsigned short* Wt3  = (unsigned short*)alloc((size_t)64 * 256 * 2);

    const int NB = (N_NODES + 255) / 256;
    const int EB = (ETOT + 255) / 256;
    const int WB = (N_NODES + 3) / 4;
    const int MB = (N_NODES + 127) / 128;

    // ---- CSR build (padded to multiple of 8 per node) ----
    hipMemsetAsync(deg,  0, (size_t)N_NODES * 4, stream);
    hipMemsetAsync(fill, 0, (size_t)N_NODES * 4, stream);
    hipMemsetAsync(eSrc, 0xFF, (size_t)EPAD_MAX * 4, stream);   // pads -> -1
    k_hist<<<EB, 256, 0, stream>>>(ei, deg);
    k_scan1<<<NB, 256, 0, stream>>>(deg, start, bsum);
    k_scan2<<<1, 256, 0, stream>>>(bsum, NB);
    k_scan3<<<NB, 256, 0, stream>>>(start, bsum);
    k_scatter<<<EB, 256, 0, stream>>>(ei, start, fill, eSrc);

    // ---- weight transposes ----
    k_wt<<<(256 * IN_CH + 255) / 256, 256, 0, stream>>>(W1, Wt1, IN_CH, 256, 256);
    k_wt<<<(256 * 256 + 255) / 256, 256, 0, stream>>>(W2, Wt2, 256, 256, 256);
    k_wt<<<(64 * 256 + 255) / 256, 256, 0, stream>>>(W3, Wt3, 256, OUT_CH, 64);

    // ---- layer 1 (fp32 x staged+converted in-GEMM) ----
    k_mfma<128, 4, 4, true><<<dim3(MB, 2), 256, 0, stream>>>(x, Wt1, hAbf, N_NODES, IN_CH, 256);
    k_logits4<<<WB, 256, 0, stream>>>(hAbf, as1, ad1, als, ald);
    k_agg4<<<WB, 256, 0, stream>>>(hAbf, start, deg, eSrc, als, ald, b1, hBbf);

    // ---- layer 2 ----
    k_mfma<128, 4, 4, false><<<dim3(MB, 2), 256, 0, stream>>>(hBbf, Wt2, hAbf, N_NODES, 256, 256);
    k_logits4<<<WB, 256, 0, stream>>>(hAbf, as2, ad2, als, ald);
    k_agg4<<<WB, 256, 0, stream>>>(hAbf, start, deg, eSrc, als, ald, b2, hBbf);

    // ---- layer 3 ----
    k_mfma<64, 2, 4, false><<<dim3(MB, 1), 256, 0, stream>>>(hBbf, Wt3, h3bf, N_NODES, 256, OUT_CH);
    k_logits1<<<WB, 256, 0, stream>>>(h3bf, as3, ad3, als, ald);
    k_agg1<<<WB, 256, 0, stream>>>(h3bf, start, deg, eSrc, als, ald, b3, out);
}